// Round 8
// baseline (1028.076 us; speedup 1.0000x reference)
//
#include <hip/hip_runtime.h>
#include <hip/hip_bf16.h>
#include <math.h>

typedef __hip_bfloat16 bf16;
typedef short s16x8 __attribute__((ext_vector_type(8)));
typedef float f32x4 __attribute__((ext_vector_type(4)));

#define B_    4
#define N1_   2048
#define N2_   512
#define D_    768
#define H_    8
#define DK_   64
#define DV_   96
#define NPOS_ 4095
#define SCALE_ 0.125f

__device__ __forceinline__ float b2f(bf16 v) { return __bfloat162float(v); }
__device__ __forceinline__ bf16  f2b(float v) { return __float2bfloat16(v); }
__device__ __forceinline__ float us2f(unsigned short u) {
    return __uint_as_float(((unsigned int)u) << 16);
}
__device__ __forceinline__ unsigned short f2bu(float v) {
    bf16 t = __float2bfloat16(v);
    return *reinterpret_cast<unsigned short*>(&t);
}
__device__ __forceinline__ float ldf(const float* p) { return *p; }
__device__ __forceinline__ float ldf(const bf16* p)  { return __bfloat162float(*p); }
__device__ __forceinline__ void stf(float* p, float v) { *p = v; }
__device__ __forceinline__ void stf(bf16* p, float v)  { *p = f2b(v); }
#define MFMA16(a, b, c) __builtin_amdgcn_mfma_f32_16x16x32_bf16((a), (b), (c), 0, 0, 0)

// ---------------------------------------------------------------------------
// Row stats for LayerNorm over D_=768: one wave per row -> (mean, rstd).
// ---------------------------------------------------------------------------
template <typename T>
__global__ __launch_bounds__(64) void stats_kernel(
    const T* __restrict__ in, float2* __restrict__ st)
{
    int row = blockIdx.x, lane = threadIdx.x;
    const T* p = in + (size_t)row * D_;
    float v[12];
    float s = 0.f;
#pragma unroll
    for (int i = 0; i < 12; i++) { v[i] = ldf(p + lane + i * 64); s += v[i]; }
#pragma unroll
    for (int o = 32; o > 0; o >>= 1) s += __shfl_down(s, o);
    float mean = __shfl(s, 0) * (1.f / 768.f);
    float var = 0.f;
#pragma unroll
    for (int i = 0; i < 12; i++) { float d = v[i] - mean; var += d * d; }
#pragma unroll
    for (int o = 32; o > 0; o >>= 1) var += __shfl_down(var, o);
    float rstd = rsqrtf(__shfl(var, 0) * (1.f / 768.f) + 1e-5f);
    if (lane == 0) st[row] = make_float2(mean, rstd);
}

// ---------------------------------------------------------------------------
// MFMA bf16 GEMM, 64x64 tile (for small-M y-stream GEMMs).
// C = (LN?(A (+A2)))[M,K] @ Bw[K,N] *cscale (+bias)(relu)(+res)
// ---------------------------------------------------------------------------
template <typename TA, typename TC, typename TR>
__global__ __launch_bounds__(256) void mgemm_kernel(
    const TA* __restrict__ A, const TA* __restrict__ A2,
    const float* __restrict__ Bw,
    TC* __restrict__ C, int M, int N, int K,
    const float2* __restrict__ lnst, const float* __restrict__ lng,
    const float* __restrict__ lnb,
    const float* __restrict__ bias, int relu, const TR* __restrict__ res,
    float cscale)
{
    __shared__ unsigned short As[64][40];
    __shared__ unsigned short Bs[64][40];
    int tid = threadIdx.x;
    int wave = tid >> 6, lane = tid & 63;
    int bm = blockIdx.y * 64, bn = blockIdx.x * 64;
    f32x4 acc[4] = {};

    int am = tid >> 2, ak = (tid & 3) * 8;
    int bn_ = tid & 63, bk = (tid >> 6) * 8;

    for (int k0 = 0; k0 < K; k0 += 32) {
        float av[8];
        if (bm + am < M) {
            const TA* ap = A + (size_t)(bm + am) * K + k0 + ak;
#pragma unroll
            for (int j = 0; j < 8; j++) av[j] = ldf(ap + j);
            if (A2) {
                const TA* ap2 = A2 + (size_t)(bm + am) * K + k0 + ak;
#pragma unroll
                for (int j = 0; j < 8; j++) av[j] += ldf(ap2 + j);
            }
            if (lnst) {
                float2 s = lnst[bm + am];
#pragma unroll
                for (int j = 0; j < 8; j++)
                    av[j] = (av[j] - s.x) * s.y * lng[k0 + ak + j] + lnb[k0 + ak + j];
            }
        } else {
#pragma unroll
            for (int j = 0; j < 8; j++) av[j] = 0.f;
        }
#pragma unroll
        for (int j = 0; j < 8; j++) As[am][ak + j] = f2bu(av[j]);
#pragma unroll
        for (int j = 0; j < 8; j++)
            Bs[bn_][bk + j] = f2bu(Bw[(size_t)(k0 + bk + j) * N + bn + bn_]);
        __syncthreads();

        s16x8 afrag = *reinterpret_cast<const s16x8*>(&As[wave * 16 + (lane & 15)][(lane >> 4) * 8]);
#pragma unroll
        for (int ns = 0; ns < 4; ns++) {
            s16x8 bfrag = *reinterpret_cast<const s16x8*>(&Bs[ns * 16 + (lane & 15)][(lane >> 4) * 8]);
            acc[ns] = MFMA16(afrag, bfrag, acc[ns]);
        }
        __syncthreads();
    }

    int col = lane & 15, rg = (lane >> 4) * 4;
#pragma unroll
    for (int ns = 0; ns < 4; ns++) {
        int n = bn + ns * 16 + col;
        float bv = bias ? bias[n] : 0.f;
#pragma unroll
        for (int r = 0; r < 4; r++) {
            int m = bm + wave * 16 + rg + r;
            if (m < M) {
                float v = acc[ns][r] * cscale + bv;
                if (relu) v = fmaxf(v, 0.f);
                size_t off = (size_t)m * N + n;
                if (res) v += ldf(res + off);
                stf(C + off, v);
            }
        }
    }
}

// ---------------------------------------------------------------------------
// MFMA bf16 GEMM, 128x128 tile (big-M GEMMs): 4 waves in 2x2, each 64x64
// (4x4 MFMA tiles) -> 64 MFMA per barrier pair. BK=32, LDS 20KB.
// Same frag recipe as mgemm_kernel (HW-verified R6/R7).
// ---------------------------------------------------------------------------
template <typename TA, typename TC, typename TR>
__global__ __launch_bounds__(256) void mgemm128_kernel(
    const TA* __restrict__ A, const float* __restrict__ Bw,
    TC* __restrict__ C, int M, int N, int K,
    const float2* __restrict__ lnst, const float* __restrict__ lng,
    const float* __restrict__ lnb,
    const float* __restrict__ bias, int relu, const TR* __restrict__ res,
    float cscale)
{
    __shared__ unsigned short As[128][40];
    __shared__ unsigned short Bs[128][40];
    int tid = threadIdx.x;
    int wave = tid >> 6, lane = tid & 63;
    int lc = lane & 15, kq = lane >> 4;
    int wm = (wave & 1) * 64, wn = (wave >> 1) * 64;
    int bm = blockIdx.y * 128, bn = blockIdx.x * 128;
    f32x4 acc[4][4] = {};

    int am = tid >> 1, ak = (tid & 1) * 16;   // A: 2 threads/row, 16 k each
    int bn_ = tid & 127, bk = (tid >> 7) * 16; // B: 16 k-rows, fixed n

    for (int k0 = 0; k0 < K; k0 += 32) {
        float av[16];
        if (bm + am < M) {
            const TA* ap = A + (size_t)(bm + am) * K + k0 + ak;
#pragma unroll
            for (int j = 0; j < 16; j++) av[j] = ldf(ap + j);
            if (lnst) {
                float2 s = lnst[bm + am];
#pragma unroll
                for (int j = 0; j < 16; j++)
                    av[j] = (av[j] - s.x) * s.y * lng[k0 + ak + j] + lnb[k0 + ak + j];
            }
        } else {
#pragma unroll
            for (int j = 0; j < 16; j++) av[j] = 0.f;
        }
#pragma unroll
        for (int j = 0; j < 16; j++) As[am][ak + j] = f2bu(av[j]);
#pragma unroll
        for (int j = 0; j < 16; j++)
            Bs[bn_][bk + j] = f2bu(Bw[(size_t)(k0 + bk + j) * N + bn + bn_]);
        __syncthreads();

        s16x8 af[4], bf[4];
#pragma unroll
        for (int mt = 0; mt < 4; mt++)
            af[mt] = *reinterpret_cast<const s16x8*>(&As[wm + mt * 16 + lc][kq * 8]);
#pragma unroll
        for (int nt = 0; nt < 4; nt++)
            bf[nt] = *reinterpret_cast<const s16x8*>(&Bs[wn + nt * 16 + lc][kq * 8]);
#pragma unroll
        for (int mt = 0; mt < 4; mt++)
#pragma unroll
            for (int nt = 0; nt < 4; nt++)
                acc[mt][nt] = MFMA16(af[mt], bf[nt], acc[mt][nt]);
        __syncthreads();
    }

#pragma unroll
    for (int mt = 0; mt < 4; mt++) {
#pragma unroll
        for (int nt = 0; nt < 4; nt++) {
            int n = bn + wn + nt * 16 + lc;
            float bv = bias ? bias[n] : 0.f;
#pragma unroll
            for (int r = 0; r < 4; r++) {
                int m = bm + wm + mt * 16 + kq * 4 + r;
                if (m < M) {
                    float v = acc[mt][nt][r] * cscale + bv;
                    if (relu) v = fmaxf(v, 0.f);
                    size_t off = (size_t)m * N + n;
                    if (res) v += ldf(res + off);
                    stf(C + off, v);
                }
            }
        }
    }
}

// ---------------------------------------------------------------------------
// Enformer positional features: pos[4095, 96] bf16.
// ---------------------------------------------------------------------------
__global__ __launch_bounds__(64) void pos_kernel(bf16* __restrict__ pos)
{
    int m = blockIdx.x * 64 + threadIdx.x;
    if (m >= NPOS_) return;
    float dist = (float)(m - 2047);
    float ad = fabsf(dist);
    float sgn = (dist > 0.f) ? 1.f : ((dist < 0.f) ? -1.f : 0.f);
    float f[48];
#pragma unroll
    for (int t = 0; t < 16; t++) {
        float hl = exp2f(3.f + (8.f / 15.f) * (float)t);
        f[t] = expf(-0.69314718056f / hl * ad);
    }
#pragma unroll
    for (int t = 0; t < 16; t++) {
        float cw = exp2f((float)(t + 1)) - 1.f;
        f[16 + t] = (cw > ad) ? 1.f : 0.f;
    }
    float pr[16];
    float mx = 0.f;
    if (ad < 0.5f) {
#pragma unroll
        for (int t = 0; t < 16; t++) pr[t] = 1e-8f;
        mx = 1e-8f;
    } else {
        float lad = logf(ad);
#pragma unroll
        for (int t = 0; t < 16; t++) {
            float mean = 128.f * (float)(t + 1);
            float cc = (mean / 64.f) * (mean / 64.f);
            float rate = mean * (1.f / 4096.f);
            float logp = (cc - 1.f) * lad - rate * ad - (lgammaf(cc) - cc * logf(rate));
            float p = expf(logp) + 1e-8f;
            pr[t] = p;
            mx = fmaxf(mx, p);
        }
    }
#pragma unroll
    for (int t = 0; t < 16; t++) f[32 + t] = pr[t] / mx;

    bf16* o = pos + (size_t)m * 96;
#pragma unroll
    for (int c = 0; c < 48; c++) { o[c] = f2b(f[c]); o[48 + c] = f2b(sgn * f[c]); }
}

// ---------------------------------------------------------------------------
// kbb[b,j,h*64+d] = kb*SCALE + rel_pos_bias[h*64+d]
// ---------------------------------------------------------------------------
__global__ __launch_bounds__(256) void kbb_kernel(
    const bf16* __restrict__ kb, const float* __restrict__ relbias,
    bf16* __restrict__ kbb)
{
    int idx = blockIdx.x * 256 + threadIdx.x;
    int fidx = idx & 511;
    kbb[idx] = f2b(b2f(kb[idx]) * SCALE_ + relbias[fidx]);
}

// ---------------------------------------------------------------------------
// MFMA attention pass 1 (unchanged from R7).
// ---------------------------------------------------------------------------
__global__ __launch_bounds__(256) void attn1_kernel(
    const bf16* __restrict__ qb, const bf16* __restrict__ kb,
    const bf16* __restrict__ kbb, const bf16* __restrict__ relq,
    const bf16* __restrict__ v2, bf16* __restrict__ out1,
    float* __restrict__ mst, float* __restrict__ lst)
{
    int it = blockIdx.x & 31;
    int bh = blockIdx.x >> 5;
    int b = bh >> 3, h = bh & 7;
    int i0 = it * 64;
    __shared__ __align__(16) unsigned short Ts[64][130];
    __shared__ __align__(16) unsigned short Ps[64][72];
    __shared__ __align__(16) unsigned short Vs[96][72];
    int tid = threadIdx.x, wave = tid >> 6, lane = tid & 63;
    int lc = lane & 15, kq = lane >> 4;
    int ibase = wave * 16 + kq * 4;

    s16x8 qf0, qf1;
    {
        const bf16* qp = qb + (size_t)(b * N1_ + i0 + wave * 16 + lc) * 512 + h * 64 + kq * 8;
        qf0 = *reinterpret_cast<const s16x8*>(qp);
        qf1 = *reinterpret_cast<const s16x8*>(qp + 32);
    }

    float m_run[4], l_run[4];
#pragma unroll
    for (int r = 0; r < 4; r++) { m_run[r] = -1e30f; l_run[r] = 0.f; }
    f32x4 oacc[6] = {};

    for (int j0 = 0; j0 < N2_; j0 += 64) {
        __syncthreads();
        int m0 = i0 + 447 - j0;
        const bf16* kbp = kbb + (size_t)(b * N2_ + j0 + wave * 16 + lc) * 512 + h * 64 + kq * 8;
        s16x8 kbf0 = *reinterpret_cast<const s16x8*>(kbp);
        s16x8 kbf1 = *reinterpret_cast<const s16x8*>(kbp + 32);
        f32x4 tacc[8] = {};
#pragma unroll
        for (int ns = 0; ns < 8; ns++) {
            int row = m0 + ns * 16 + lc;
            if (row < 0) row = 0;
            const bf16* rp = relq + (size_t)row * 512 + h * 64 + kq * 8;
            s16x8 rf0 = *reinterpret_cast<const s16x8*>(rp);
            s16x8 rf1 = *reinterpret_cast<const s16x8*>(rp + 32);
            tacc[ns] = MFMA16(kbf0, rf0, tacc[ns]);
            tacc[ns] = MFMA16(kbf1, rf1, tacc[ns]);
        }
        {
            int jj = tid & 63, dvb = (tid >> 6) * 24;
            const unsigned short* vp = (const unsigned short*)
                (v2 + (size_t)(b * N2_ + j0 + jj) * 768 + h * 96 + dvb);
#pragma unroll
            for (int t = 0; t < 24; t++) Vs[dvb + t][jj] = vp[t];
        }
#pragma unroll
        for (int ns = 0; ns < 8; ns++)
#pragma unroll
            for (int r = 0; r < 4; r++)
                Ts[wave * 16 + kq * 4 + r][ns * 16 + lc] = f2bu(tacc[ns][r]);
        __syncthreads();

        f32x4 cacc[4] = {};
#pragma unroll
        for (int ns = 0; ns < 4; ns++) {
            const bf16* kp = kb + (size_t)(b * N2_ + j0 + ns * 16 + lc) * 512 + h * 64 + kq * 8;
            s16x8 kf0 = *reinterpret_cast<const s16x8*>(kp);
            s16x8 kf1 = *reinterpret_cast<const s16x8*>(kp + 32);
            cacc[ns] = MFMA16(qf0, kf0, cacc[ns]);
            cacc[ns] = MFMA16(qf1, kf1, cacc[ns]);
        }
        float Lv[4][4];
#pragma unroll
        for (int ns = 0; ns < 4; ns++) {
            int jloc = ns * 16 + lc;
#pragma unroll
            for (int r = 0; r < 4; r++) {
                int mm = (ibase + r) - jloc + 64;
                Lv[ns][r] = cacc[ns][r] + us2f(Ts[jloc][mm]);
            }
        }
#pragma unroll
        for (int r = 0; r < 4; r++) {
            float v = fmaxf(fmaxf(Lv[0][r], Lv[1][r]), fmaxf(Lv[2][r], Lv[3][r]));
            v = fmaxf(v, __shfl_xor(v, 1));
            v = fmaxf(v, __shfl_xor(v, 2));
            v = fmaxf(v, __shfl_xor(v, 4));
            v = fmaxf(v, __shfl_xor(v, 8));
            float mn = fmaxf(m_run[r], v);
            float alpha = __expf(m_run[r] - mn);
            m_run[r] = mn;
            float s = 0.f;
#pragma unroll
            for (int ns = 0; ns < 4; ns++) {
                float p = __expf(Lv[ns][r] - mn);
                Lv[ns][r] = p;
                s += p;
            }
            s += __shfl_xor(s, 1);
            s += __shfl_xor(s, 2);
            s += __shfl_xor(s, 4);
            s += __shfl_xor(s, 8);
            l_run[r] = l_run[r] * alpha + s;
#pragma unroll
            for (int ns6 = 0; ns6 < 6; ns6++) oacc[ns6][r] *= alpha;
        }
#pragma unroll
        for (int ns = 0; ns < 4; ns++)
#pragma unroll
            for (int r = 0; r < 4; r++)
                Ps[ibase + r][ns * 16 + lc] = f2bu(Lv[ns][r]);
#pragma unroll
        for (int kk = 0; kk < 2; kk++) {
            s16x8 pf = *reinterpret_cast<const s16x8*>(&Ps[wave * 16 + lc][kq * 8 + kk * 32]);
#pragma unroll
            for (int ns6 = 0; ns6 < 6; ns6++) {
                s16x8 vf = *reinterpret_cast<const s16x8*>(&Vs[ns6 * 16 + lc][kq * 8 + kk * 32]);
                oacc[ns6] = MFMA16(pf, vf, oacc[ns6]);
            }
        }
    }

    float invl[4];
#pragma unroll
    for (int r = 0; r < 4; r++) invl[r] = 1.f / l_run[r];
#pragma unroll
    for (int ns6 = 0; ns6 < 6; ns6++)
#pragma unroll
        for (int r = 0; r < 4; r++)
            out1[(size_t)(b * N1_ + i0 + ibase + r) * 768 + h * 96 + ns6 * 16 + lc]
                = f2b(oacc[ns6][r] * invl[r]);
    if (lc == 0) {
#pragma unroll
        for (int r = 0; r < 4; r++) {
            mst[(size_t)bh * N1_ + i0 + ibase + r] = m_run[r];
            lst[(size_t)bh * N1_ + i0 + ibase + r] = l_run[r];
        }
    }
}

// ---------------------------------------------------------------------------
// MFMA attention pass 2 (unchanged from R7).
// ---------------------------------------------------------------------------
__global__ __launch_bounds__(256) void attn2_kernel(
    const bf16* __restrict__ qb, const bf16* __restrict__ kb,
    const bf16* __restrict__ kbb, const bf16* __restrict__ relq,
    const bf16* __restrict__ v1, bf16* __restrict__ out2halves,
    const float* __restrict__ mst, const float* __restrict__ lst)
{
    int half = blockIdx.x & 1;
    int jt = (blockIdx.x >> 1) & 7;
    int bh = blockIdx.x >> 4;
    int b = bh >> 3, h = bh & 7;
    int j0 = jt * 64;
    __shared__ __align__(16) unsigned short Ts[64][130];
    __shared__ __align__(16) unsigned short Ps[64][72];
    __shared__ __align__(16) unsigned short Vs[96][72];
    int tid = threadIdx.x, wave = tid >> 6, lane = tid & 63;
    int lc = lane & 15, kq = lane >> 4;
    int ibase = wave * 16 + kq * 4;

    const bf16* kbp = kbb + (size_t)(b * N2_ + j0 + wave * 16 + lc) * 512 + h * 64 + kq * 8;
    s16x8 kbf0 = *reinterpret_cast<const s16x8*>(kbp);
    s16x8 kbf1 = *reinterpret_cast<const s16x8*>(kbp + 32);
    s16x8 kf0[4], kf1[4];
#pragma unroll
    for (int ns = 0; ns < 4; ns++) {
        const bf16* kp = kb + (size_t)(b * N2_ + j0 + ns * 16 + lc) * 512 + h * 64 + kq * 8;
        kf0[ns] = *reinterpret_cast<const s16x8*>(kp);
        kf1[ns] = *reinterpret_cast<const s16x8*>(kp + 32);
    }

    f32x4 oacc[6] = {};
    for (int i0 = half * 1024; i0 < half * 1024 + 1024; i0 += 64) {
        __syncthreads();
        int m0 = i0 + 447 - j0;
        f32x4 tacc[8] = {};
#pragma unroll
        for (int ns = 0; ns < 8; ns++) {
            int row = m0 + ns * 16 + lc;
            if (row < 0) row = 0;
            const bf16* rp = relq + (size_t)row * 512 + h * 64 + kq * 8;
            s16x8 rf0 = *reinterpret_cast<const s16x8*>(rp);
            s16x8 rf1 = *reinterpret_cast<const s16x8*>(rp + 32);
            tacc[ns] = MFMA16(kbf0, rf0, tacc[ns]);
            tacc[ns] = MFMA16(kbf1, rf1, tacc[ns]);
        }
        {
            int ii = tid & 63, dvb = (tid >> 6) * 24;
            const unsigned short* vp = (const unsigned short*)
                (v1 + (size_t)(b * N1_ + i0 + ii) * 768 + h * 96 + dvb);
#pragma unroll
            for (int t = 0; t < 24; t++) Vs[dvb + t][ii] = vp[t];
        }
#pragma unroll
        for (int ns = 0; ns < 8; ns++)
#pragma unroll
            for (int r = 0; r < 4; r++)
                Ts[wave * 16 + kq * 4 + r][ns * 16 + lc] = f2bu(tacc[ns][r]);
        __syncthreads();

        const bf16* qp = qb + (size_t)(b * N1_ + i0 + wave * 16 + lc) * 512 + h * 64 + kq * 8;
        s16x8 qf0 = *reinterpret_cast<const s16x8*>(qp);
        s16x8 qf1 = *reinterpret_cast<const s16x8*>(qp + 32);
        f32x4 cacc[4] = {};
#pragma unroll
        for (int ns = 0; ns < 4; ns++) {
            cacc[ns] = MFMA16(qf0, kf0[ns], cacc[ns]);
            cacc[ns] = MFMA16(qf1, kf1[ns], cacc[ns]);
        }
        float mi[4], invli[4];
#pragma unroll
        for (int r = 0; r < 4; r++) {
            mi[r] = mst[(size_t)bh * N1_ + i0 + ibase + r];
            invli[r] = 1.f / lst[(size_t)bh * N1_ + i0 + ibase + r];
        }
#pragma unroll
        for (int ns = 0; ns < 4; ns++) {
            int jloc = ns * 16 + lc;
#pragma unroll
            for (int r = 0; r < 4; r++) {
                int mm = (ibase + r) - jloc + 64;
                float L = cacc[ns][r] + us2f(Ts[jloc][mm]);
                Ps[jloc][ibase + r] = f2bu(__expf(L - mi[r]) * invli[r]);
            }
        }
        __syncthreads();
#pragma unroll
        for (int kk = 0; kk < 2; kk++) {
            s16x8 pf = *reinterpret_cast<const s16x8*>(&Ps[wave * 16 + lc][kq * 8 + kk * 32]);
#pragma unroll
            for (int ns6 = 0; ns6 < 6; ns6++) {
                s16x8 vf = *reinterpret_cast<const s16x8*>(&Vs[ns6 * 16 + lc][kq * 8 + kk * 32]);
                oacc[ns6] = MFMA16(pf, vf, oacc[ns6]);
            }
        }
    }

    bf16* outp = out2halves + (size_t)half * B_ * N2_ * 768;
#pragma unroll
    for (int ns6 = 0; ns6 < 6; ns6++)
#pragma unroll
        for (int r = 0; r < 4; r++)
            outp[(size_t)(b * N2_ + j0 + ibase + r) * 768 + h * 96 + ns6 * 16 + lc]
                = f2b(oacc[ns6][r]);
}

// ---------------------------------------------------------------------------
extern "C" void kernel_launch(void* const* d_in, const int* in_sizes, int n_in,
                              void* d_out, int out_size, void* d_ws, size_t ws_size,
                              hipStream_t stream)
{
    (void)in_sizes; (void)n_in; (void)out_size; (void)ws_size;
    const float* x      = (const float*)d_in[0];
    const float* y0     = (const float*)d_in[1];
    const float* Wres   = (const float*)d_in[2];
    const float* lnx_g  = (const float*)d_in[3];
    const float* lnx_b  = (const float*)d_in[4];
    const float* lny_g  = (const float*)d_in[5];
    const float* lny_b  = (const float*)d_in[6];
    const float* Wq     = (const float*)d_in[7];
    const float* Wk     = (const float*)d_in[8];
    const float* Wv1    = (const float*)d_in[9];
    const float* Wv2    = (const float*)d_in[10];
    const float* Wo1    = (const float*)d_in[11];
    const float* bo1    = (const float*)d_in[12];
    const float* Wo2    = (const float*)d_in[13];
    const float* bo2    = (const float*)d_in[14];
    const float* Wrel   = (const float*)d_in[15];
    const float* rel_pb = (const float*)d_in[16];
    const float* fx_g   = (const float*)d_in[17];
    const float* fx_b   = (const float*)d_in[18];
    const float* fx_w1  = (const float*)d_in[19];
    const float* fx_b1  = (const float*)d_in[20];
    const float* fx_w2  = (const float*)d_in[21];
    const float* fx_b2  = (const float*)d_in[22];
    const float* fy_g   = (const float*)d_in[23];
    const float* fy_b   = (const float*)d_in[24];
    const float* fy_w1  = (const float*)d_in[25];
    const float* fy_b1  = (const float*)d_in[26];
    const float* fy_w2  = (const float*)d_in[27];
    const float* fy_b2  = (const float*)d_in[28];

    float* out_x = (float*)d_out;                          // [4,2048,768] fp32
    float* out_y = out_x + (size_t)B_ * N1_ * D_;          // [4,512,768] fp32
    bf16* out1 = (bf16*)d_out;  // attn out1 parked in d_out (dies before fp32 writes)

    // ---- workspace (~59 MB) ----
    char* W = (char*)d_ws;
    size_t o = 0;
    auto alloc = [&](size_t bytes) { char* p = W + o; o += (bytes + 255) & ~(size_t)255; return p; };
    bf16*   qb   = (bf16*)alloc((size_t)B_ * N1_ * 512 * 2);   // 8.39 MB ┐
    bf16*   kb   = (bf16*)alloc((size_t)B_ * N2_ * 512 * 2);   // 2.10 MB │ x4 overlays
    bf16*   posb = (bf16*)alloc((size_t)NPOS_ * 96 * 2);       // 0.79 MB │ this span
    bf16*   relq = (bf16*)alloc((size_t)NPOS_ * 512 * 2);      // 4.19 MB ┘
    bf16*   v1b  = (bf16*)alloc((size_t)B_ * N1_ * 768 * 2);   // 12.58 MB ┐ hx overlays
    bf16*   hx2  = (bf16*)alloc((size_t)B_ * N1_ * 768 * 2);   // 12.58 MB ┘ (25.17 MB)
    bf16*   v2b  = (bf16*)alloc((size_t)B_ * N2_ * 768 * 2);   // 3.15 MB  (y4 overlays)
    float*  yb   = (float*)alloc((size_t)B_ * N2_ * 768 * 4);  // 6.29 MB (f32 residual)
    bf16*   hy   = (bf16*)alloc((size_t)B_ * N2_ * 1536 * 2);  // 6.29 MB
    bf16*   kbbb = (bf16*)alloc((size_t)B_ * N2_ * 512 * 2);   // 2.10 MB
    float2* sx   = (float2*)alloc((size_t)B_ * N1_ * 8);
    float2* sy   = (float2*)alloc((size_t)B_ * N2_ * 8);
    float2* sx4  = (float2*)alloc((size_t)B_ * N1_ * 8);
    float2* sy4  = (float2*)alloc((size_t)B_ * N2_ * 8);
    float*  mst  = (float*)alloc((size_t)B_ * H_ * N1_ * 4);
    float*  lst  = (float*)alloc((size_t)B_ * H_ * N1_ * 4);
    bf16* x4 = qb;            // after attention, qb..relq span is dead
    bf16* y4 = v2b;           // after attention, v2b is dead
    bf16* hx = v1b;           // FFNx hidden spans v1b+hx2 (after Wo2 done)
    bf16* out2h = hx2;        // two 3.15MB half-buffers inside hx2 (dead before hx)

    dim3 blk(256);
    // 1. y = y0 @ W_res (f32 residual), M=2048 -> 64-tile
    mgemm_kernel<float, float, float><<<dim3(12, 32), blk, 0, stream>>>(
        y0, nullptr, Wres, yb, B_ * N2_, D_, 1536,
        nullptr, nullptr, nullptr, nullptr, 0, nullptr, 1.f);
    // 2. LN row stats
    stats_kernel<float><<<B_ * N1_, 64, 0, stream>>>(x, sx);
    stats_kernel<float><<<B_ * N2_, 64, 0, stream>>>(yb, sy);
    // 3. fused-LN projections (q pre-scaled by SCALE); M=8192 -> 128-tile
    mgemm128_kernel<float, bf16, float><<<dim3(4, 64), blk, 0, stream>>>(
        x, Wq, qb, B_ * N1_, 512, D_, sx, lnx_g, lnx_b, nullptr, 0, nullptr, SCALE_);
    mgemm_kernel<float, bf16, float><<<dim3(8, 32), blk, 0, stream>>>(
        yb, nullptr, Wk, kb, B_ * N2_, 512, D_, sy, lny_g, lny_b, nullptr, 0, nullptr, 1.f);
    mgemm128_kernel<float, bf16, float><<<dim3(6, 64), blk, 0, stream>>>(
        x, Wv1, v1b, B_ * N1_, D_, D_, sx, lnx_g, lnx_b, nullptr, 0, nullptr, 1.f);
    mgemm_kernel<float, bf16, float><<<dim3(12, 32), blk, 0, stream>>>(
        yb, nullptr, Wv2, v2b, B_ * N2_, D_, D_, sy, lny_g, lny_b, nullptr, 0, nullptr, 1.f);
    // 4. positional features + rel_q + kbb
    pos_kernel<<<(NPOS_ + 63) / 64, 64, 0, stream>>>(posb);
    mgemm128_kernel<bf16, bf16, float><<<dim3(4, 32), blk, 0, stream>>>(
        posb, Wrel, relq, NPOS_, 512, 96,
        nullptr, nullptr, nullptr, nullptr, 0, nullptr, 1.f);
    kbb_kernel<<<(B_ * N2_ * 512) / 256, blk, 0, stream>>>(kb, rel_pb, kbbb);
    // 5. MFMA attention
    attn1_kernel<<<B_ * H_ * (N1_ / 64), blk, 0, stream>>>(
        qb, kb, kbbb, relq, v2b, out1, mst, lst);
    attn2_kernel<<<B_ * H_ * (N2_ / 64) * 2, blk, 0, stream>>>(
        qb, kb, kbbb, relq, v1b, out2h, mst, lst);
    // 6. output projections + residuals (Wo2 sums the two out2 halves via A2)
    mgemm128_kernel<bf16, bf16, float><<<dim3(6, 64), blk, 0, stream>>>(
        out1, Wo1, x4, B_ * N1_, D_, D_,
        nullptr, nullptr, nullptr, bo1, 0, x, 1.f);
    mgemm_kernel<bf16, bf16, float><<<dim3(12, 32), blk, 0, stream>>>(
        out2h, out2h + (size_t)B_ * N2_ * 768, Wo2, y4, B_ * N2_, D_, D_,
        nullptr, nullptr, nullptr, bo2, 0, yb, 1.f);
    // 7. FFN x -> out_x fp32 (overwrites out1 bytes; out1 dead)
    stats_kernel<bf16><<<B_ * N1_, 64, 0, stream>>>(x4, sx4);
    mgemm128_kernel<bf16, bf16, float><<<dim3(12, 64), blk, 0, stream>>>(
        x4, fx_w1, hx, B_ * N1_, 1536, D_, sx4, fx_g, fx_b, fx_b1, 1, nullptr, 1.f);
    mgemm128_kernel<bf16, float, bf16><<<dim3(6, 64), blk, 0, stream>>>(
        hx, fx_w2, out_x, B_ * N1_, D_, 1536,
        nullptr, nullptr, nullptr, fx_b2, 0, x4, 1.f);
    // 8. FFN y -> out_y fp32
    stats_kernel<bf16><<<B_ * N2_, 64, 0, stream>>>(y4, sy4);
    mgemm_kernel<bf16, bf16, float><<<dim3(24, 32), blk, 0, stream>>>(
        y4, nullptr, fy_w1, hy, B_ * N2_, 1536, D_, sy4, fy_g, fy_b, fy_b1, 1, nullptr, 1.f);
    mgemm_kernel<bf16, float, bf16><<<dim3(12, 32), blk, 0, stream>>>(
        hy, nullptr, fy_w2, out_y, B_ * N2_, D_, 1536,
        nullptr, nullptr, nullptr, fy_b2, 0, y4, 1.f);
}

// Round 9
// 940.361 us; speedup vs baseline: 1.0933x; 1.0933x over previous
//
#include <hip/hip_runtime.h>
#include <hip/hip_bf16.h>
#include <math.h>

typedef __hip_bfloat16 bf16;
typedef short s16x8 __attribute__((ext_vector_type(8)));
typedef float f32x4 __attribute__((ext_vector_type(4)));

#define B_    4
#define N1_   2048
#define N2_   512
#define D_    768
#define H_    8
#define DK_   64
#define DV_   96
#define NPOS_ 4095
#define SCALE_ 0.125f

__device__ __forceinline__ float b2f(bf16 v) { return __bfloat162float(v); }
__device__ __forceinline__ bf16  f2b(float v) { return __float2bfloat16(v); }
__device__ __forceinline__ float us2f(unsigned short u) {
    return __uint_as_float(((unsigned int)u) << 16);
}
__device__ __forceinline__ unsigned short f2bu(float v) {
    bf16 t = __float2bfloat16(v);
    return *reinterpret_cast<unsigned short*>(&t);
}
__device__ __forceinline__ float ldf(const float* p) { return *p; }
__device__ __forceinline__ float ldf(const bf16* p)  { return __bfloat162float(*p); }
__device__ __forceinline__ void stf(float* p, float v) { *p = v; }
__device__ __forceinline__ void stf(bf16* p, float v)  { *p = f2b(v); }
#define MFMA16(a, b, c) __builtin_amdgcn_mfma_f32_16x16x32_bf16((a), (b), (c), 0, 0, 0)

// ---------------------------------------------------------------------------
// Weight pre-pack: fp32 -> bf16, optionally interleaving two matrices
// side-by-side (dstride != sn). 12 segments, one dispatch.
// ---------------------------------------------------------------------------
struct PackArgs {
    const float* src[12];
    unsigned n[12];
    unsigned sn[12];
    unsigned dstride[12];
    unsigned doff[12];
    unsigned blk0[13];
};

__global__ __launch_bounds__(256) void pack_kernel(PackArgs pa, bf16* __restrict__ dst)
{
    int bid = blockIdx.x;
    int s = 0;
    while (s < 11 && bid >= (int)pa.blk0[s + 1]) s++;
    unsigned base = (unsigned)(bid - pa.blk0[s]) * 8192u;
    const float* src = pa.src[s];
    unsigned n = pa.n[s], sn = pa.sn[s], dstride = pa.dstride[s], doff = pa.doff[s];
    bool plain = (dstride == sn);
    for (unsigned e = threadIdx.x; e < 8192u; e += 256u) {
        unsigned idx = base + e;
        if (idx >= n) break;
        float v = src[idx];
        unsigned o;
        if (plain) o = doff + idx;
        else if (sn == 512u) o = doff + (idx >> 9) * dstride + (idx & 511u);
        else { unsigned k = idx / 768u; o = doff + k * dstride + (idx - k * 768u); }
        dst[o] = f2b(v);
    }
}

// ---------------------------------------------------------------------------
// Row stats for LayerNorm over D_=768: one wave per row -> (mean, rstd).
// ---------------------------------------------------------------------------
template <typename T>
__global__ __launch_bounds__(64) void stats_kernel(
    const T* __restrict__ in, float2* __restrict__ st)
{
    int row = blockIdx.x, lane = threadIdx.x;
    const T* p = in + (size_t)row * D_;
    float v[12];
    float s = 0.f;
#pragma unroll
    for (int i = 0; i < 12; i++) { v[i] = ldf(p + lane + i * 64); s += v[i]; }
#pragma unroll
    for (int o = 32; o > 0; o >>= 1) s += __shfl_down(s, o);
    float mean = __shfl(s, 0) * (1.f / 768.f);
    float var = 0.f;
#pragma unroll
    for (int i = 0; i < 12; i++) { float d = v[i] - mean; var += d * d; }
#pragma unroll
    for (int o = 32; o > 0; o >>= 1) var += __shfl_down(var, o);
    float rstd = rsqrtf(__shfl(var, 0) * (1.f / 768.f) + 1e-5f);
    if (lane == 0) st[row] = make_float2(mean, rstd);
}

// ---------------------------------------------------------------------------
// MFMA bf16 GEMM, 64x64 tile. Bw is packed bf16. Optional split epilogue
// (Cq/Cv): col<512 -> Cq (stride 512, x sscale; optionally Cq2 = v*SCALE+qbias2),
// col>=512 -> Cv (stride 768).
// ---------------------------------------------------------------------------
template <typename TA, typename TC, typename TR>
__global__ __launch_bounds__(256) void mgemm_kernel(
    const TA* __restrict__ A, const TA* __restrict__ A2,
    const bf16* __restrict__ Bw,
    TC* __restrict__ C, int M, int N, int K,
    const float2* __restrict__ lnst, const float* __restrict__ lng,
    const float* __restrict__ lnb,
    const float* __restrict__ bias, int relu, const TR* __restrict__ res,
    float cscale,
    bf16* __restrict__ Cq, bf16* __restrict__ Cv,
    bf16* __restrict__ Cq2, const float* __restrict__ qbias2, float sscale)
{
    __shared__ unsigned short As[64][40];
    __shared__ unsigned short Bs[64][40];
    int tid = threadIdx.x;
    int wave = tid >> 6, lane = tid & 63;
    int bm = blockIdx.y * 64, bn = blockIdx.x * 64;
    f32x4 acc[4] = {};

    int am = tid >> 2, ak = (tid & 3) * 8;
    int bn_ = tid & 63, bk = (tid >> 6) * 8;

    for (int k0 = 0; k0 < K; k0 += 32) {
        float av[8];
        if (bm + am < M) {
            const TA* ap = A + (size_t)(bm + am) * K + k0 + ak;
#pragma unroll
            for (int j = 0; j < 8; j++) av[j] = ldf(ap + j);
            if (A2) {
                const TA* ap2 = A2 + (size_t)(bm + am) * K + k0 + ak;
#pragma unroll
                for (int j = 0; j < 8; j++) av[j] += ldf(ap2 + j);
            }
            if (lnst) {
                float2 s = lnst[bm + am];
#pragma unroll
                for (int j = 0; j < 8; j++)
                    av[j] = (av[j] - s.x) * s.y * lng[k0 + ak + j] + lnb[k0 + ak + j];
            }
        } else {
#pragma unroll
            for (int j = 0; j < 8; j++) av[j] = 0.f;
        }
#pragma unroll
        for (int j = 0; j < 8; j++) As[am][ak + j] = f2bu(av[j]);
        const unsigned short* bw = (const unsigned short*)Bw;
#pragma unroll
        for (int j = 0; j < 8; j++)
            Bs[bn_][bk + j] = bw[(size_t)(k0 + bk + j) * N + bn + bn_];
        __syncthreads();

        s16x8 afrag = *reinterpret_cast<const s16x8*>(&As[wave * 16 + (lane & 15)][(lane >> 4) * 8]);
#pragma unroll
        for (int ns = 0; ns < 4; ns++) {
            s16x8 bfrag = *reinterpret_cast<const s16x8*>(&Bs[ns * 16 + (lane & 15)][(lane >> 4) * 8]);
            acc[ns] = MFMA16(afrag, bfrag, acc[ns]);
        }
        __syncthreads();
    }

    int col = lane & 15, rg = (lane >> 4) * 4;
#pragma unroll
    for (int ns = 0; ns < 4; ns++) {
        int n = bn + ns * 16 + col;
        float bv = (!Cq && bias) ? bias[n] : 0.f;
#pragma unroll
        for (int r = 0; r < 4; r++) {
            int m = bm + wave * 16 + rg + r;
            if (m >= M) continue;
            float vr = acc[ns][r];
            if (Cq) {
                if (n < 512) {
                    Cq[(size_t)m * 512 + n] = f2b(vr * sscale);
                    if (Cq2) Cq2[(size_t)m * 512 + n] = f2b(vr * SCALE_ + qbias2[n]);
                } else {
                    Cv[(size_t)m * 768 + n - 512] = f2b(vr);
                }
            } else {
                float v = vr * cscale + bv;
                if (relu) v = fmaxf(v, 0.f);
                size_t off = (size_t)m * N + n;
                if (res) v += ldf(res + off);
                stf(C + off, v);
            }
        }
    }
}

// ---------------------------------------------------------------------------
// MFMA bf16 GEMM, 128x128 tile: 4 waves 2x2, 64 MFMA per barrier pair.
// Same split-epilogue options as mgemm_kernel.
// ---------------------------------------------------------------------------
template <typename TA, typename TC, typename TR>
__global__ __launch_bounds__(256) void mgemm128_kernel(
    const TA* __restrict__ A, const bf16* __restrict__ Bw,
    TC* __restrict__ C, int M, int N, int K,
    const float2* __restrict__ lnst, const float* __restrict__ lng,
    const float* __restrict__ lnb,
    const float* __restrict__ bias, int relu, const TR* __restrict__ res,
    float cscale,
    bf16* __restrict__ Cq, bf16* __restrict__ Cv,
    bf16* __restrict__ Cq2, const float* __restrict__ qbias2, float sscale)
{
    __shared__ unsigned short As[128][40];
    __shared__ unsigned short Bs[128][40];
    int tid = threadIdx.x;
    int wave = tid >> 6, lane = tid & 63;
    int lc = lane & 15, kq = lane >> 4;
    int wm = (wave & 1) * 64, wn = (wave >> 1) * 64;
    int bm = blockIdx.y * 128, bn = blockIdx.x * 128;
    f32x4 acc[4][4] = {};

    int am = tid >> 1, ak = (tid & 1) * 16;
    int bn_ = tid & 127, bk = (tid >> 7) * 16;

    for (int k0 = 0; k0 < K; k0 += 32) {
        float av[16];
        if (bm + am < M) {
            const TA* ap = A + (size_t)(bm + am) * K + k0 + ak;
#pragma unroll
            for (int j = 0; j < 16; j++) av[j] = ldf(ap + j);
            if (lnst) {
                float2 s = lnst[bm + am];
#pragma unroll
                for (int j = 0; j < 16; j++)
                    av[j] = (av[j] - s.x) * s.y * lng[k0 + ak + j] + lnb[k0 + ak + j];
            }
        } else {
#pragma unroll
            for (int j = 0; j < 16; j++) av[j] = 0.f;
        }
#pragma unroll
        for (int j = 0; j < 16; j++) As[am][ak + j] = f2bu(av[j]);
        const unsigned short* bw = (const unsigned short*)Bw;
#pragma unroll
        for (int j = 0; j < 16; j++)
            Bs[bn_][bk + j] = bw[(size_t)(k0 + bk + j) * N + bn + bn_];
        __syncthreads();

        s16x8 af[4], bf[4];
#pragma unroll
        for (int mt = 0; mt < 4; mt++)
            af[mt] = *reinterpret_cast<const s16x8*>(&As[wm + mt * 16 + lc][kq * 8]);
#pragma unroll
        for (int nt = 0; nt < 4; nt++)
            bf[nt] = *reinterpret_cast<const s16x8*>(&Bs[wn + nt * 16 + lc][kq * 8]);
#pragma unroll
        for (int mt = 0; mt < 4; mt++)
#pragma unroll
            for (int nt = 0; nt < 4; nt++)
                acc[mt][nt] = MFMA16(af[mt], bf[nt], acc[mt][nt]);
        __syncthreads();
    }

#pragma unroll
    for (int mt = 0; mt < 4; mt++) {
#pragma unroll
        for (int nt = 0; nt < 4; nt++) {
            int n = bn + wn + nt * 16 + lc;
            float bv = (!Cq && bias) ? bias[n] : 0.f;
#pragma unroll
            for (int r = 0; r < 4; r++) {
                int m = bm + wm + mt * 16 + kq * 4 + r;
                if (m >= M) continue;
                float vr = acc[mt][nt][r];
                if (Cq) {
                    if (n < 512) {
                        Cq[(size_t)m * 512 + n] = f2b(vr * sscale);
                        if (Cq2) Cq2[(size_t)m * 512 + n] = f2b(vr * SCALE_ + qbias2[n]);
                    } else {
                        Cv[(size_t)m * 768 + n - 512] = f2b(vr);
                    }
                } else {
                    float v = vr * cscale + bv;
                    if (relu) v = fmaxf(v, 0.f);
                    size_t off = (size_t)m * N + n;
                    if (res) v += ldf(res + off);
                    stf(C + off, v);
                }
            }
        }
    }
}

// ---------------------------------------------------------------------------
// Enformer positional features: pos[4095, 96] bf16.
// ---------------------------------------------------------------------------
__global__ __launch_bounds__(64) void pos_kernel(bf16* __restrict__ pos)
{
    int m = blockIdx.x * 64 + threadIdx.x;
    if (m >= NPOS_) return;
    float dist = (float)(m - 2047);
    float ad = fabsf(dist);
    float sgn = (dist > 0.f) ? 1.f : ((dist < 0.f) ? -1.f : 0.f);
    float f[48];
#pragma unroll
    for (int t = 0; t < 16; t++) {
        float hl = exp2f(3.f + (8.f / 15.f) * (float)t);
        f[t] = expf(-0.69314718056f / hl * ad);
    }
#pragma unroll
    for (int t = 0; t < 16; t++) {
        float cw = exp2f((float)(t + 1)) - 1.f;
        f[16 + t] = (cw > ad) ? 1.f : 0.f;
    }
    float pr[16];
    float mx = 0.f;
    if (ad < 0.5f) {
#pragma unroll
        for (int t = 0; t < 16; t++) pr[t] = 1e-8f;
        mx = 1e-8f;
    } else {
        float lad = logf(ad);
#pragma unroll
        for (int t = 0; t < 16; t++) {
            float mean = 128.f * (float)(t + 1);
            float cc = (mean / 64.f) * (mean / 64.f);
            float rate = mean * (1.f / 4096.f);
            float logp = (cc - 1.f) * lad - rate * ad - (lgammaf(cc) - cc * logf(rate));
            float p = expf(logp) + 1e-8f;
            pr[t] = p;
            mx = fmaxf(mx, p);
        }
    }
#pragma unroll
    for (int t = 0; t < 16; t++) f[32 + t] = pr[t] / mx;

    bf16* o = pos + (size_t)m * 96;
#pragma unroll
    for (int c = 0; c < 48; c++) { o[c] = f2b(f[c]); o[48 + c] = f2b(sgn * f[c]); }
}

// ---------------------------------------------------------------------------
// MFMA attention pass 1 (unchanged from R7/R8).
// ---------------------------------------------------------------------------
__global__ __launch_bounds__(256) void attn1_kernel(
    const bf16* __restrict__ qb, const bf16* __restrict__ kb,
    const bf16* __restrict__ kbb, const bf16* __restrict__ relq,
    const bf16* __restrict__ v2, bf16* __restrict__ out1,
    float* __restrict__ mst, float* __restrict__ lst)
{
    int it = blockIdx.x & 31;
    int bh = blockIdx.x >> 5;
    int b = bh >> 3, h = bh & 7;
    int i0 = it * 64;
    __shared__ __align__(16) unsigned short Ts[64][130];
    __shared__ __align__(16) unsigned short Ps[64][72];
    __shared__ __align__(16) unsigned short Vs[96][72];
    int tid = threadIdx.x, wave = tid >> 6, lane = tid & 63;
    int lc = lane & 15, kq = lane >> 4;
    int ibase = wave * 16 + kq * 4;

    s16x8 qf0, qf1;
    {
        const bf16* qp = qb + (size_t)(b * N1_ + i0 + wave * 16 + lc) * 512 + h * 64 + kq * 8;
        qf0 = *reinterpret_cast<const s16x8*>(qp);
        qf1 = *reinterpret_cast<const s16x8*>(qp + 32);
    }

    float m_run[4], l_run[4];
#pragma unroll
    for (int r = 0; r < 4; r++) { m_run[r] = -1e30f; l_run[r] = 0.f; }
    f32x4 oacc[6] = {};

    for (int j0 = 0; j0 < N2_; j0 += 64) {
        __syncthreads();
        int m0 = i0 + 447 - j0;
        const bf16* kbp = kbb + (size_t)(b * N2_ + j0 + wave * 16 + lc) * 512 + h * 64 + kq * 8;
        s16x8 kbf0 = *reinterpret_cast<const s16x8*>(kbp);
        s16x8 kbf1 = *reinterpret_cast<const s16x8*>(kbp + 32);
        f32x4 tacc[8] = {};
#pragma unroll
        for (int ns = 0; ns < 8; ns++) {
            int row = m0 + ns * 16 + lc;
            if (row < 0) row = 0;
            const bf16* rp = relq + (size_t)row * 512 + h * 64 + kq * 8;
            s16x8 rf0 = *reinterpret_cast<const s16x8*>(rp);
            s16x8 rf1 = *reinterpret_cast<const s16x8*>(rp + 32);
            tacc[ns] = MFMA16(kbf0, rf0, tacc[ns]);
            tacc[ns] = MFMA16(kbf1, rf1, tacc[ns]);
        }
        {
            int jj = tid & 63, dvb = (tid >> 6) * 24;
            const unsigned short* vp = (const unsigned short*)
                (v2 + (size_t)(b * N2_ + j0 + jj) * 768 + h * 96 + dvb);
#pragma unroll
            for (int t = 0; t < 24; t++) Vs[dvb + t][jj] = vp[t];
        }
#pragma unroll
        for (int ns = 0; ns < 8; ns++)
#pragma unroll
            for (int r = 0; r < 4; r++)
                Ts[wave * 16 + kq * 4 + r][ns * 16 + lc] = f2bu(tacc[ns][r]);
        __syncthreads();

        f32x4 cacc[4] = {};
#pragma unroll
        for (int ns = 0; ns < 4; ns++) {
            const bf16* kp = kb + (size_t)(b * N2_ + j0 + ns * 16 + lc) * 512 + h * 64 + kq * 8;
            s16x8 kf0 = *reinterpret_cast<const s16x8*>(kp);
            s16x8 kf1 = *reinterpret_cast<const s16x8*>(kp + 32);
            cacc[ns] = MFMA16(qf0, kf0, cacc[ns]);
            cacc[ns] = MFMA16(qf1, kf1, cacc[ns]);
        }
        float Lv[4][4];
#pragma unroll
        for (int ns = 0; ns < 4; ns++) {
            int jloc = ns * 16 + lc;
#pragma unroll
            for (int r = 0; r < 4; r++) {
                int mm = (ibase + r) - jloc + 64;
                Lv[ns][r] = cacc[ns][r] + us2f(Ts[jloc][mm]);
            }
        }
#pragma unroll
        for (int r = 0; r < 4; r++) {
            float v = fmaxf(fmaxf(Lv[0][r], Lv[1][r]), fmaxf(Lv[2][r], Lv[3][r]));
            v = fmaxf(v, __shfl_xor(v, 1));
            v = fmaxf(v, __shfl_xor(v, 2));
            v = fmaxf(v, __shfl_xor(v, 4));
            v = fmaxf(v, __shfl_xor(v, 8));
            float mn = fmaxf(m_run[r], v);
            float alpha = __expf(m_run[r] - mn);
            m_run[r] = mn;
            float s = 0.f;
#pragma unroll
            for (int ns = 0; ns < 4; ns++) {
                float p = __expf(Lv[ns][r] - mn);
                Lv[ns][r] = p;
                s += p;
            }
            s += __shfl_xor(s, 1);
            s += __shfl_xor(s, 2);
            s += __shfl_xor(s, 4);
            s += __shfl_xor(s, 8);
            l_run[r] = l_run[r] * alpha + s;
#pragma unroll
            for (int ns6 = 0; ns6 < 6; ns6++) oacc[ns6][r] *= alpha;
        }
#pragma unroll
        for (int ns = 0; ns < 4; ns++)
#pragma unroll
            for (int r = 0; r < 4; r++)
                Ps[ibase + r][ns * 16 + lc] = f2bu(Lv[ns][r]);
#pragma unroll
        for (int kk = 0; kk < 2; kk++) {
            s16x8 pf = *reinterpret_cast<const s16x8*>(&Ps[wave * 16 + lc][kq * 8 + kk * 32]);
#pragma unroll
            for (int ns6 = 0; ns6 < 6; ns6++) {
                s16x8 vf = *reinterpret_cast<const s16x8*>(&Vs[ns6 * 16 + lc][kq * 8 + kk * 32]);
                oacc[ns6] = MFMA16(pf, vf, oacc[ns6]);
            }
        }
    }

    float invl[4];
#pragma unroll
    for (int r = 0; r < 4; r++) invl[r] = 1.f / l_run[r];
#pragma unroll
    for (int ns6 = 0; ns6 < 6; ns6++)
#pragma unroll
        for (int r = 0; r < 4; r++)
            out1[(size_t)(b * N1_ + i0 + ibase + r) * 768 + h * 96 + ns6 * 16 + lc]
                = f2b(oacc[ns6][r] * invl[r]);
    if (lc == 0) {
#pragma unroll
        for (int r = 0; r < 4; r++) {
            mst[(size_t)bh * N1_ + i0 + ibase + r] = m_run[r];
            lst[(size_t)bh * N1_ + i0 + ibase + r] = l_run[r];
        }
    }
}

// ---------------------------------------------------------------------------
// MFMA attention pass 2 (unchanged from R7/R8).
// ---------------------------------------------------------------------------
__global__ __launch_bounds__(256) void attn2_kernel(
    const bf16* __restrict__ qb, const bf16* __restrict__ kb,
    const bf16* __restrict__ kbb, const bf16* __restrict__ relq,
    const bf16* __restrict__ v1, bf16* __restrict__ out2halves,
    const float* __restrict__ mst, const float* __restrict__ lst)
{
    int half = blockIdx.x & 1;
    int jt = (blockIdx.x >> 1) & 7;
    int bh = blockIdx.x >> 4;
    int b = bh >> 3, h = bh & 7;
    int j0 = jt * 64;
    __shared__ __align__(16) unsigned short Ts[64][130];
    __shared__ __align__(16) unsigned short Ps[64][72];
    __shared__ __align__(16) unsigned short Vs[96][72];
    int tid = threadIdx.x, wave = tid >> 6, lane = tid & 63;
    int lc = lane & 15, kq = lane >> 4;
    int ibase = wave * 16 + kq * 4;

    const bf16* kbp = kbb + (size_t)(b * N2_ + j0 + wave * 16 + lc) * 512 + h * 64 + kq * 8;
    s16x8 kbf0 = *reinterpret_cast<const s16x8*>(kbp);
    s16x8 kbf1 = *reinterpret_cast<const s16x8*>(kbp + 32);
    s16x8 kf0[4], kf1[4];
#pragma unroll
    for (int ns = 0; ns < 4; ns++) {
        const bf16* kp = kb + (size_t)(b * N2_ + j0 + ns * 16 + lc) * 512 + h * 64 + kq * 8;
        kf0[ns] = *reinterpret_cast<const s16x8*>(kp);
        kf1[ns] = *reinterpret_cast<const s16x8*>(kp + 32);
    }

    f32x4 oacc[6] = {};
    for (int i0 = half * 1024; i0 < half * 1024 + 1024; i0 += 64) {
        __syncthreads();
        int m0 = i0 + 447 - j0;
        f32x4 tacc[8] = {};
#pragma unroll
        for (int ns = 0; ns < 8; ns++) {
            int row = m0 + ns * 16 + lc;
            if (row < 0) row = 0;
            const bf16* rp = relq + (size_t)row * 512 + h * 64 + kq * 8;
            s16x8 rf0 = *reinterpret_cast<const s16x8*>(rp);
            s16x8 rf1 = *reinterpret_cast<const s16x8*>(rp + 32);
            tacc[ns] = MFMA16(kbf0, rf0, tacc[ns]);
            tacc[ns] = MFMA16(kbf1, rf1, tacc[ns]);
        }
        {
            int ii = tid & 63, dvb = (tid >> 6) * 24;
            const unsigned short* vp = (const unsigned short*)
                (v1 + (size_t)(b * N1_ + i0 + ii) * 768 + h * 96 + dvb);
#pragma unroll
            for (int t = 0; t < 24; t++) Vs[dvb + t][ii] = vp[t];
        }
#pragma unroll
        for (int ns = 0; ns < 8; ns++)
#pragma unroll
            for (int r = 0; r < 4; r++)
                Ts[wave * 16 + kq * 4 + r][ns * 16 + lc] = f2bu(tacc[ns][r]);
        __syncthreads();

        const bf16* qp = qb + (size_t)(b * N1_ + i0 + wave * 16 + lc) * 512 + h * 64 + kq * 8;
        s16x8 qf0 = *reinterpret_cast<const s16x8*>(qp);
        s16x8 qf1 = *reinterpret_cast<const s16x8*>(qp + 32);
        f32x4 cacc[4] = {};
#pragma unroll
        for (int ns = 0; ns < 4; ns++) {
            cacc[ns] = MFMA16(qf0, kf0[ns], cacc[ns]);
            cacc[ns] = MFMA16(qf1, kf1[ns], cacc[ns]);
        }
        float mi[4], invli[4];
#pragma unroll
        for (int r = 0; r < 4; r++) {
            mi[r] = mst[(size_t)bh * N1_ + i0 + ibase + r];
            invli[r] = 1.f / lst[(size_t)bh * N1_ + i0 + ibase + r];
        }
#pragma unroll
        for (int ns = 0; ns < 4; ns++) {
            int jloc = ns * 16 + lc;
#pragma unroll
            for (int r = 0; r < 4; r++) {
                int mm = (ibase + r) - jloc + 64;
                float L = cacc[ns][r] + us2f(Ts[jloc][mm]);
                Ps[jloc][ibase + r] = f2bu(__expf(L - mi[r]) * invli[r]);
            }
        }
        __syncthreads();
#pragma unroll
        for (int kk = 0; kk < 2; kk++) {
            s16x8 pf = *reinterpret_cast<const s16x8*>(&Ps[wave * 16 + lc][kq * 8 + kk * 32]);
#pragma unroll
            for (int ns6 = 0; ns6 < 6; ns6++) {
                s16x8 vf = *reinterpret_cast<const s16x8*>(&Vs[ns6 * 16 + lc][kq * 8 + kk * 32]);
                oacc[ns6] = MFMA16(pf, vf, oacc[ns6]);
            }
        }
    }

    bf16* outp = out2halves + (size_t)half * B_ * N2_ * 768;
#pragma unroll
    for (int ns6 = 0; ns6 < 6; ns6++)
#pragma unroll
        for (int r = 0; r < 4; r++)
            outp[(size_t)(b * N2_ + j0 + ibase + r) * 768 + h * 96 + ns6 * 16 + lc]
                = f2b(oacc[ns6][r]);
}

// ---------------------------------------------------------------------------
extern "C" void kernel_launch(void* const* d_in, const int* in_sizes, int n_in,
                              void* d_out, int out_size, void* d_ws, size_t ws_size,
                              hipStream_t stream)
{
    (void)in_sizes; (void)n_in; (void)out_size; (void)ws_size;
    const float* x      = (const float*)d_in[0];
    const float* y0     = (const float*)d_in[1];
    const float* Wres   = (const float*)d_in[2];
    const float* lnx_g  = (const float*)d_in[3];
    const float* lnx_b  = (const float*)d_in[4];
    const float* lny_g  = (const float*)d_in[5];
    const float* lny_b  = (const float*)d_in[6];
    const float* Wq     = (const float*)d_in[7];
    const float* Wk     = (const float*)d_in[8];
    const float* Wv1    = (const float*)d_in[9];
    const float* Wv2    = (const float*)d_in[10];
    const float* Wo1    = (const float*)d_in[11];
    const float* bo1    = (const float*)d_in[12];
    const float* Wo2    = (const float*)d_in[13];
    const float* bo2    = (const float*)d_in[14];
    const float* Wrel   = (const float*)d_in[15];
    const float* rel_pb = (const float*)d_in[16];
    const float* fx_g   = (const float*)d_in[17];
    const float* fx_b   = (const float*)d_in[18];
    const float* fx_w1  = (const float*)d_in[19];
    const float* fx_b1  = (const float*)d_in[20];
    const float* fx_w2  = (const float*)d_in[21];
    const float* fx_b2  = (const float*)d_in[22];
    const float* fy_g   = (const float*)d_in[23];
    const float* fy_b   = (const float*)d_in[24];
    const float* fy_w1  = (const float*)d_in[25];
    const float* fy_b1  = (const float*)d_in[26];
    const float* fy_w2  = (const float*)d_in[27];
    const float* fy_b2  = (const float*)d_in[28];

    float* out_x = (float*)d_out;                          // [4,2048,768] fp32
    float* out_y = out_x + (size_t)B_ * N1_ * D_;          // [4,512,768] fp32
    bf16* out1 = (bf16*)d_out;  // attn out1 parked in d_out (dies before fp32 writes)

    // ---- workspace (~70 MB) ----
    char* W = (char*)d_ws;
    size_t o = 0;
    auto alloc = [&](size_t bytes) { char* p = W + o; o += (bytes + 255) & ~(size_t)255; return p; };
    bf16*   qb   = (bf16*)alloc((size_t)B_ * N1_ * 512 * 2);   // 8.39 MB ┐
    bf16*   kb   = (bf16*)alloc((size_t)B_ * N2_ * 512 * 2);   // 2.10 MB │ x4 overlays
    bf16*   posb = (bf16*)alloc((size_t)NPOS_ * 96 * 2);       // 0.79 MB │ this span
    bf16*   relq = (bf16*)alloc((size_t)NPOS_ * 512 * 2);      // 4.19 MB ┘
    bf16*   v1b  = (bf16*)alloc((size_t)B_ * N1_ * 768 * 2);   // 12.58 MB ┐ hx overlays
    bf16*   hx2  = (bf16*)alloc((size_t)B_ * N1_ * 768 * 2);   // 12.58 MB ┘ (25.17 MB)
    bf16*   v2b  = (bf16*)alloc((size_t)B_ * N2_ * 768 * 2);   // 3.15 MB  (y4 overlays)
    float*  yb   = (float*)alloc((size_t)B_ * N2_ * 768 * 4);  // 6.29 MB (f32 residual)
    bf16*   kbbb = (bf16*)alloc((size_t)B_ * N2_ * 512 * 2);   // 2.10 MB
    bf16*   wpool= (bf16*)alloc((size_t)9093120 * 2);          // 17.34 MB packed weights
    float2* sx   = (float2*)alloc((size_t)B_ * N1_ * 8);
    float2* sy   = (float2*)alloc((size_t)B_ * N2_ * 8);
    float2* sx4  = (float2*)alloc((size_t)B_ * N1_ * 8);
    float2* sy4  = (float2*)alloc((size_t)B_ * N2_ * 8);
    float*  mst  = (float*)alloc((size_t)B_ * H_ * N1_ * 4);
    float*  lst  = (float*)alloc((size_t)B_ * H_ * N1_ * 4);
    bf16* x4 = qb;            // after attention, qb..relq span is dead
    bf16* y4 = v2b;           // after attention, v2b is dead
    bf16* hx = v1b;           // FFNx hidden spans v1b+hx2 (after Wo2 done)
    bf16* out2h = hx2;        // two 3.15MB half-buffers inside hx2 (dead before hx)
    bf16* hy = v1b;           // FFNy hidden reuses hx region (hx dead by then)

    // packed weight offsets (elements)
    const unsigned OW_RES = 0, OW_QV1 = 1179648, OW_KV2 = 2162688, OW_O1 = 3145728,
                   OW_O2 = 3735552, OW_REL = 4325376, OW_FXW1 = 4374528,
                   OW_FXW2 = 5554176, OW_FYW1 = 6733824, OW_FYW2 = 7913472;
    bf16* wres_b = wpool + OW_RES;   bf16* wqv1b = wpool + OW_QV1;
    bf16* wkv2b  = wpool + OW_KV2;   bf16* wo1b  = wpool + OW_O1;
    bf16* wo2b   = wpool + OW_O2;    bf16* wrelb = wpool + OW_REL;
    bf16* fxw1b  = wpool + OW_FXW1;  bf16* fxw2b = wpool + OW_FXW2;
    bf16* fyw1b  = wpool + OW_FYW1;  bf16* fyw2b = wpool + OW_FYW2;

    PackArgs pa;
    const float* srcs[12] = {Wres, Wq, Wv1, Wk, Wv2, Wo1, Wo2, Wrel,
                             fx_w1, fx_w2, fy_w1, fy_w2};
    unsigned ns_[12]  = {1179648, 393216, 589824, 393216, 589824, 589824, 589824,
                         49152, 1179648, 1179648, 1179648, 1179648};
    unsigned sns[12]  = {768, 512, 768, 512, 768, 768, 768, 512, 1536, 768, 1536, 768};
    unsigned dss[12]  = {768, 1280, 1280, 1280, 1280, 768, 768, 512, 1536, 768, 1536, 768};
    unsigned dfs[12]  = {OW_RES, OW_QV1, OW_QV1 + 512, OW_KV2, OW_KV2 + 512,
                         OW_O1, OW_O2, OW_REL, OW_FXW1, OW_FXW2, OW_FYW1, OW_FYW2};
    unsigned cum = 0;
    for (int i = 0; i < 12; i++) {
        pa.src[i] = srcs[i]; pa.n[i] = ns_[i]; pa.sn[i] = sns[i];
        pa.dstride[i] = dss[i]; pa.doff[i] = dfs[i];
        pa.blk0[i] = cum;
        cum += (ns_[i] + 8191) / 8192;
    }
    pa.blk0[12] = cum;

    dim3 blk(256);
    // 0. pack weights fp32 -> bf16 (+ QV1/KV2 interleave)
    pack_kernel<<<cum, blk, 0, stream>>>(pa, wpool);
    // 1. y = y0 @ W_res (f32 residual)
    mgemm_kernel<float, float, float><<<dim3(12, 32), blk, 0, stream>>>(
        y0, nullptr, wres_b, yb, B_ * N2_, D_, 1536,
        nullptr, nullptr, nullptr, nullptr, 0, nullptr, 1.f,
        nullptr, nullptr, nullptr, nullptr, 0.f);
    // 2. LN row stats
    stats_kernel<float><<<B_ * N1_, 64, 0, stream>>>(x, sx);
    stats_kernel<float><<<B_ * N2_, 64, 0, stream>>>(yb, sy);
    // 3. fused projections: [q|v1] and [k|v2] (+kbb third output)
    mgemm128_kernel<float, bf16, float><<<dim3(10, 64), blk, 0, stream>>>(
        x, wqv1b, (bf16*)nullptr, B_ * N1_, 1280, D_, sx, lnx_g, lnx_b,
        nullptr, 0, nullptr, 1.f, qb, v1b, nullptr, nullptr, SCALE_);
    mgemm_kernel<float, bf16, float><<<dim3(20, 32), blk, 0, stream>>>(
        yb, nullptr, wkv2b, (bf16*)nullptr, B_ * N2_, 1280, D_, sy, lny_g, lny_b,
        nullptr, 0, nullptr, 1.f, kb, v2b, kbbb, rel_pb, 1.f);
    // 4. positional features + rel_q
    pos_kernel<<<(NPOS_ + 63) / 64, 64, 0, stream>>>(posb);
    mgemm128_kernel<bf16, bf16, float><<<dim3(4, 32), blk, 0, stream>>>(
        posb, wrelb, relq, NPOS_, 512, 96,
        nullptr, nullptr, nullptr, nullptr, 0, nullptr, 1.f,
        nullptr, nullptr, nullptr, nullptr, 0.f);
    // 5. MFMA attention
    attn1_kernel<<<B_ * H_ * (N1_ / 64), blk, 0, stream>>>(
        qb, kb, kbbb, relq, v2b, out1, mst, lst);
    attn2_kernel<<<B_ * H_ * (N2_ / 64) * 2, blk, 0, stream>>>(
        qb, kb, kbbb, relq, v1b, out2h, mst, lst);
    // 6. output projections + residuals
    mgemm128_kernel<bf16, bf16, float><<<dim3(6, 64), blk, 0, stream>>>(
        out1, wo1b, x4, B_ * N1_, D_, D_,
        nullptr, nullptr, nullptr, bo1, 0, x, 1.f,
        nullptr, nullptr, nullptr, nullptr, 0.f);
    mgemm_kernel<bf16, bf16, float><<<dim3(12, 32), blk, 0, stream>>>(
        out2h, out2h + (size_t)B_ * N2_ * 768, wo2b, y4, B_ * N2_, D_, D_,
        nullptr, nullptr, nullptr, bo2, 0, yb, 1.f,
        nullptr, nullptr, nullptr, nullptr, 0.f);
    // 7. FFN x -> out_x fp32
    stats_kernel<bf16><<<B_ * N1_, 64, 0, stream>>>(x4, sx4);
    mgemm128_kernel<bf16, bf16, float><<<dim3(12, 64), blk, 0, stream>>>(
        x4, fxw1b, hx, B_ * N1_, 1536, D_, sx4, fx_g, fx_b, fx_b1, 1, nullptr, 1.f,
        nullptr, nullptr, nullptr, nullptr, 0.f);
    mgemm128_kernel<bf16, float, bf16><<<dim3(6, 64), blk, 0, stream>>>(
        hx, fxw2b, out_x, B_ * N1_, D_, 1536,
        nullptr, nullptr, nullptr, fx_b2, 0, x4, 1.f,
        nullptr, nullptr, nullptr, nullptr, 0.f);
    // 8. FFN y -> out_y fp32 (hy reuses hx region; hx dead after FFNx-w2)
    stats_kernel<bf16><<<B_ * N2_, 64, 0, stream>>>(y4, sy4);
    mgemm_kernel<bf16, bf16, float><<<dim3(24, 32), blk, 0, stream>>>(
        y4, nullptr, fyw1b, hy, B_ * N2_, 1536, D_, sy4, fy_g, fy_b, fy_b1, 1, nullptr, 1.f,
        nullptr, nullptr, nullptr, nullptr, 0.f);
    mgemm_kernel<bf16, float, bf16><<<dim3(12, 32), blk, 0, stream>>>(
        hy, nullptr, fyw2b, out_y, B_ * N2_, D_, 1536,
        nullptr, nullptr, nullptr, fy_b2, 0, y4, 1.f,
        nullptr, nullptr, nullptr, nullptr, 0.f);
}

// Round 10
// 810.539 us; speedup vs baseline: 1.2684x; 1.1602x over previous
//
#include <hip/hip_runtime.h>
#include <hip/hip_bf16.h>
#include <math.h>

typedef __hip_bfloat16 bf16;
typedef short s16x8 __attribute__((ext_vector_type(8)));
typedef float f32x4 __attribute__((ext_vector_type(4)));

#define B_    4
#define N1_   2048
#define N2_   512
#define D_    768
#define H_    8
#define DK_   64
#define DV_   96
#define NPOS_ 4095
#define SCALE_ 0.125f

__device__ __forceinline__ float b2f(bf16 v) { return __bfloat162float(v); }
__device__ __forceinline__ bf16  f2b(float v) { return __float2bfloat16(v); }
__device__ __forceinline__ float us2f(unsigned short u) {
    return __uint_as_float(((unsigned int)u) << 16);
}
__device__ __forceinline__ unsigned short f2bu(float v) {
    bf16 t = __float2bfloat16(v);
    return *reinterpret_cast<unsigned short*>(&t);
}
__device__ __forceinline__ float ldf(const float* p) { return *p; }
__device__ __forceinline__ float ldf(const bf16* p)  { return __bfloat162float(*p); }
__device__ __forceinline__ void stf(float* p, float v) { *p = v; }
__device__ __forceinline__ void stf(bf16* p, float v)  { *p = f2b(v); }
#define MFMA16(a, b, c) __builtin_amdgcn_mfma_f32_16x16x32_bf16((a), (b), (c), 0, 0, 0)

// ---------------------------------------------------------------------------
// Transpose-pack: W[K][N] fp32 -> W^T[n][k] bf16 at dst+dbase, row stride drow.
// 32k x 64n tiles through LDS; reads and writes coalesced/vector.
// ---------------------------------------------------------------------------
struct PackT {
    const float* src[12];
    unsigned K[12], N[12], dbase[12], drow[12];
    unsigned t0[13];
};

__global__ __launch_bounds__(256) void packT_kernel(PackT pa, bf16* __restrict__ dst)
{
    int bid = blockIdx.x, s = 0;
    while (s < 11 && bid >= (int)pa.t0[s + 1]) s++;
    int t = bid - (int)pa.t0[s];
    unsigned K = pa.K[s], N = pa.N[s];
    unsigned ntk = K >> 5;
    unsigned k0 = (t % ntk) << 5, n0 = (t / ntk) << 6;
    __shared__ float tile[32][65];
    const float* src = pa.src[s];
    int tid = threadIdx.x;
    {
        int e = tid * 8, k = e >> 6, n = e & 63;
        const float* p = src + (size_t)(k0 + k) * N + n0 + n;
#pragma unroll
        for (int j = 0; j < 8; j++) tile[k][n + j] = p[j];
    }
    __syncthreads();
    {
        int f = tid * 8, n = f >> 5, k = f & 31;
        bf16* q = dst + (size_t)pa.dbase[s] + (size_t)(n0 + n) * pa.drow[s] + k0 + k;
#pragma unroll
        for (int j = 0; j < 8; j++) q[j] = f2b(tile[k + j][n]);
    }
}

// ---------------------------------------------------------------------------
// Full LayerNorm over D_=768 -> bf16 out. One wave per row.
// ---------------------------------------------------------------------------
template <typename T>
__global__ __launch_bounds__(64) void lnfull_kernel(
    const T* __restrict__ in, const float* __restrict__ g,
    const float* __restrict__ b, bf16* __restrict__ out)
{
    int row = blockIdx.x, lane = threadIdx.x;
    const T* p = in + (size_t)row * D_;
    float v[12];
    float s = 0.f;
#pragma unroll
    for (int i = 0; i < 12; i++) { v[i] = ldf(p + lane + i * 64); s += v[i]; }
#pragma unroll
    for (int o = 32; o > 0; o >>= 1) s += __shfl_down(s, o);
    float mean = __shfl(s, 0) * (1.f / 768.f);
    float var = 0.f;
#pragma unroll
    for (int i = 0; i < 12; i++) { float d = v[i] - mean; var += d * d; }
#pragma unroll
    for (int o = 32; o > 0; o >>= 1) var += __shfl_down(var, o);
    float rstd = rsqrtf(__shfl(var, 0) * (1.f / 768.f) + 1e-5f);
    bf16* q = out + (size_t)row * D_;
#pragma unroll
    for (int i = 0; i < 12; i++) {
        int c = lane + i * 64;
        q[c] = f2b((v[i] - mean) * rstd * g[c] + b[c]);
    }
}

// ---------------------------------------------------------------------------
// MFMA bf16 GEMM, 128x128 tile, BK=64, vector staging. B from W^T[n][k].
// AM: 0 = bf16 A raw copy (requires M % 128 == 0).
// Split epilogue: Cq (n<512, x sscale) / Cv (n>=512).
// ---------------------------------------------------------------------------
template <int AM, typename TC, typename TR>
__global__ __launch_bounds__(256) void mgemm128_kernel(
    const void* __restrict__ Av, const bf16* __restrict__ BwT,
    TC* __restrict__ C, int M, int N, int K,
    const float* __restrict__ bias, int relu, const TR* __restrict__ res,
    bf16* __restrict__ Cq, bf16* __restrict__ Cv, float sscale)
{
    __shared__ __align__(16) unsigned short As[128][72];
    __shared__ __align__(16) unsigned short Bs[128][72];
    int tid = threadIdx.x, wave = tid >> 6, lane = tid & 63;
    int lc = lane & 15, kq = lane >> 4;
    int wm = (wave & 1) * 64, wn = (wave >> 1) * 64;
    int bm = blockIdx.y * 128, bn = blockIdx.x * 128;
    f32x4 acc[4][4] = {};
    int am = tid >> 1, ak = (tid & 1) * 32;
    int bn_ = tid & 127, bk = (tid >> 7) * 32;
    const unsigned short* bwt = (const unsigned short*)BwT;

    for (int k0 = 0; k0 < K; k0 += 64) {
        {
            const unsigned short* ap = (const unsigned short*)Av + (size_t)(bm + am) * K + k0 + ak;
#pragma unroll
            for (int j = 0; j < 4; j++)
                *reinterpret_cast<s16x8*>(&As[am][ak + j * 8]) =
                    *reinterpret_cast<const s16x8*>(ap + j * 8);
        }
        {
            const unsigned short* bp = bwt + (size_t)(bn + bn_) * K + k0 + bk;
#pragma unroll
            for (int j = 0; j < 4; j++)
                *reinterpret_cast<s16x8*>(&Bs[bn_][bk + j * 8]) =
                    *reinterpret_cast<const s16x8*>(bp + j * 8);
        }
        __syncthreads();
#pragma unroll
        for (int kh = 0; kh < 2; kh++) {
            s16x8 af[4], bf[4];
#pragma unroll
            for (int mt = 0; mt < 4; mt++)
                af[mt] = *reinterpret_cast<const s16x8*>(&As[wm + mt * 16 + lc][kh * 32 + kq * 8]);
#pragma unroll
            for (int nt = 0; nt < 4; nt++)
                bf[nt] = *reinterpret_cast<const s16x8*>(&Bs[wn + nt * 16 + lc][kh * 32 + kq * 8]);
#pragma unroll
            for (int mt = 0; mt < 4; mt++)
#pragma unroll
                for (int nt = 0; nt < 4; nt++)
                    acc[mt][nt] = MFMA16(af[mt], bf[nt], acc[mt][nt]);
        }
        __syncthreads();
    }

#pragma unroll
    for (int mt = 0; mt < 4; mt++) {
#pragma unroll
        for (int nt = 0; nt < 4; nt++) {
            int n = bn + wn + nt * 16 + lc;
            float bv = (!Cq && bias) ? bias[n] : 0.f;
#pragma unroll
            for (int r = 0; r < 4; r++) {
                int m = bm + wm + mt * 16 + kq * 4 + r;
                float vr = acc[mt][nt][r];
                if (Cq) {
                    if (n < 512) Cq[(size_t)m * 512 + n] = f2b(vr * sscale);
                    else         Cv[(size_t)m * 768 + n - 512] = f2b(vr);
                } else {
                    float v = vr + bv;
                    if (relu) v = fmaxf(v, 0.f);
                    size_t off = (size_t)m * N + n;
                    if (res) v += ldf(res + off);
                    stf(C + off, v);
                }
            }
        }
    }
}

// ---------------------------------------------------------------------------
// MFMA bf16 GEMM, 64x64 tile, BK=32, vector staging. B from W^T[n][k].
// AM: 0 = bf16 copy, 1 = fp32 A, 2 = bf16 A + A2 sum. M guarded.
// Split epilogue: Cq (n<512, x sscale; Cq2 = v*SCALE + qbias2) / Cv.
// ---------------------------------------------------------------------------
template <int AM, typename TC, typename TR>
__global__ __launch_bounds__(256) void mgemm64_kernel(
    const void* __restrict__ Av, const void* __restrict__ A2v,
    const bf16* __restrict__ BwT,
    TC* __restrict__ C, int M, int N, int K,
    const float* __restrict__ bias, int relu, const TR* __restrict__ res,
    bf16* __restrict__ Cq, bf16* __restrict__ Cv,
    bf16* __restrict__ Cq2, const float* __restrict__ qbias2, float sscale)
{
    __shared__ unsigned short As[64][40];
    __shared__ unsigned short Bs[64][40];
    int tid = threadIdx.x, wave = tid >> 6, lane = tid & 63;
    int bm = blockIdx.y * 64, bn = blockIdx.x * 64;
    f32x4 acc[4] = {};
    int am = tid >> 2, ak = (tid & 3) * 8;
    int bn_ = tid & 63, bk = (tid >> 6) * 8;
    const unsigned short* bwt = (const unsigned short*)BwT;

    for (int k0 = 0; k0 < K; k0 += 32) {
        if (AM == 0) {
            s16x8 va = {};
            if (bm + am < M)
                va = *reinterpret_cast<const s16x8*>(
                    (const unsigned short*)Av + (size_t)(bm + am) * K + k0 + ak);
            *reinterpret_cast<s16x8*>(&As[am][ak]) = va;
        } else if (AM == 1) {
            const float* ap = (const float*)Av + (size_t)(bm + am) * K + k0 + ak;
#pragma unroll
            for (int j = 0; j < 8; j++)
                As[am][ak + j] = (bm + am < M) ? f2bu(ap[j]) : (unsigned short)0;
        } else {
            s16x8 va = {}, vb = {};
            if (bm + am < M) {
                va = *reinterpret_cast<const s16x8*>(
                    (const unsigned short*)Av + (size_t)(bm + am) * K + k0 + ak);
                vb = *reinterpret_cast<const s16x8*>(
                    (const unsigned short*)A2v + (size_t)(bm + am) * K + k0 + ak);
            }
#pragma unroll
            for (int j = 0; j < 8; j++)
                As[am][ak + j] = f2bu(us2f((unsigned short)va[j]) + us2f((unsigned short)vb[j]));
        }
        *reinterpret_cast<s16x8*>(&Bs[bn_][bk]) =
            *reinterpret_cast<const s16x8*>(bwt + (size_t)(bn + bn_) * K + k0 + bk);
        __syncthreads();

        s16x8 afrag = *reinterpret_cast<const s16x8*>(&As[wave * 16 + (lane & 15)][(lane >> 4) * 8]);
#pragma unroll
        for (int ns = 0; ns < 4; ns++) {
            s16x8 bfrag = *reinterpret_cast<const s16x8*>(&Bs[ns * 16 + (lane & 15)][(lane >> 4) * 8]);
            acc[ns] = MFMA16(afrag, bfrag, acc[ns]);
        }
        __syncthreads();
    }

    int col = lane & 15, rg = (lane >> 4) * 4;
#pragma unroll
    for (int ns = 0; ns < 4; ns++) {
        int n = bn + ns * 16 + col;
        float bv = (!Cq && bias) ? bias[n] : 0.f;
#pragma unroll
        for (int r = 0; r < 4; r++) {
            int m = bm + wave * 16 + rg + r;
            if (m >= M) continue;
            float vr = acc[ns][r];
            if (Cq) {
                if (n < 512) {
                    Cq[(size_t)m * 512 + n] = f2b(vr * sscale);
                    if (Cq2) Cq2[(size_t)m * 512 + n] = f2b(vr * SCALE_ + qbias2[n]);
                } else {
                    Cv[(size_t)m * 768 + n - 512] = f2b(vr);
                }
            } else {
                float v = vr + bv;
                if (relu) v = fmaxf(v, 0.f);
                size_t off = (size_t)m * N + n;
                if (res) v += ldf(res + off);
                stf(C + off, v);
            }
        }
    }
}

// ---------------------------------------------------------------------------
// Enformer positional features: pos[4095, 96] bf16.
// ---------------------------------------------------------------------------
__global__ __launch_bounds__(64) void pos_kernel(bf16* __restrict__ pos)
{
    int m = blockIdx.x * 64 + threadIdx.x;
    if (m >= NPOS_) return;
    float dist = (float)(m - 2047);
    float ad = fabsf(dist);
    float sgn = (dist > 0.f) ? 1.f : ((dist < 0.f) ? -1.f : 0.f);
    float f[48];
#pragma unroll
    for (int t = 0; t < 16; t++) {
        float hl = exp2f(3.f + (8.f / 15.f) * (float)t);
        f[t] = expf(-0.69314718056f / hl * ad);
    }
#pragma unroll
    for (int t = 0; t < 16; t++) {
        float cw = exp2f((float)(t + 1)) - 1.f;
        f[16 + t] = (cw > ad) ? 1.f : 0.f;
    }
    float pr[16];
    float mx = 0.f;
    if (ad < 0.5f) {
#pragma unroll
        for (int t = 0; t < 16; t++) pr[t] = 1e-8f;
        mx = 1e-8f;
    } else {
        float lad = logf(ad);
#pragma unroll
        for (int t = 0; t < 16; t++) {
            float mean = 128.f * (float)(t + 1);
            float cc = (mean / 64.f) * (mean / 64.f);
            float rate = mean * (1.f / 4096.f);
            float logp = (cc - 1.f) * lad - rate * ad - (lgammaf(cc) - cc * logf(rate));
            float p = expf(logp) + 1e-8f;
            pr[t] = p;
            mx = fmaxf(mx, p);
        }
    }
#pragma unroll
    for (int t = 0; t < 16; t++) f[32 + t] = pr[t] / mx;

    bf16* o = pos + (size_t)m * 96;
#pragma unroll
    for (int c = 0; c < 48; c++) { o[c] = f2b(f[c]); o[48 + c] = f2b(sgn * f[c]); }
}

// ---------------------------------------------------------------------------
// MFMA attention pass 1 (unchanged from R7-R9).
// ---------------------------------------------------------------------------
__global__ __launch_bounds__(256) void attn1_kernel(
    const bf16* __restrict__ qb, const bf16* __restrict__ kb,
    const bf16* __restrict__ kbb, const bf16* __restrict__ relq,
    const bf16* __restrict__ v2, bf16* __restrict__ out1,
    float* __restrict__ mst, float* __restrict__ lst)
{
    int it = blockIdx.x & 31;
    int bh = blockIdx.x >> 5;
    int b = bh >> 3, h = bh & 7;
    int i0 = it * 64;
    __shared__ __align__(16) unsigned short Ts[64][130];
    __shared__ __align__(16) unsigned short Ps[64][72];
    __shared__ __align__(16) unsigned short Vs[96][72];
    int tid = threadIdx.x, wave = tid >> 6, lane = tid & 63;
    int lc = lane & 15, kq = lane >> 4;
    int ibase = wave * 16 + kq * 4;

    s16x8 qf0, qf1;
    {
        const bf16* qp = qb + (size_t)(b * N1_ + i0 + wave * 16 + lc) * 512 + h * 64 + kq * 8;
        qf0 = *reinterpret_cast<const s16x8*>(qp);
        qf1 = *reinterpret_cast<const s16x8*>(qp + 32);
    }

    float m_run[4], l_run[4];
#pragma unroll
    for (int r = 0; r < 4; r++) { m_run[r] = -1e30f; l_run[r] = 0.f; }
    f32x4 oacc[6] = {};

    for (int j0 = 0; j0 < N2_; j0 += 64) {
        __syncthreads();
        int m0 = i0 + 447 - j0;
        const bf16* kbp = kbb + (size_t)(b * N2_ + j0 + wave * 16 + lc) * 512 + h * 64 + kq * 8;
        s16x8 kbf0 = *reinterpret_cast<const s16x8*>(kbp);
        s16x8 kbf1 = *reinterpret_cast<const s16x8*>(kbp + 32);
        f32x4 tacc[8] = {};
#pragma unroll
        for (int ns = 0; ns < 8; ns++) {
            int row = m0 + ns * 16 + lc;
            if (row < 0) row = 0;
            const bf16* rp = relq + (size_t)row * 512 + h * 64 + kq * 8;
            s16x8 rf0 = *reinterpret_cast<const s16x8*>(rp);
            s16x8 rf1 = *reinterpret_cast<const s16x8*>(rp + 32);
            tacc[ns] = MFMA16(kbf0, rf0, tacc[ns]);
            tacc[ns] = MFMA16(kbf1, rf1, tacc[ns]);
        }
        {
            int jj = tid & 63, dvb = (tid >> 6) * 24;
            const unsigned short* vp = (const unsigned short*)
                (v2 + (size_t)(b * N2_ + j0 + jj) * 768 + h * 96 + dvb);
#pragma unroll
            for (int t = 0; t < 24; t++) Vs[dvb + t][jj] = vp[t];
        }
#pragma unroll
        for (int ns = 0; ns < 8; ns++)
#pragma unroll
            for (int r = 0; r < 4; r++)
                Ts[wave * 16 + kq * 4 + r][ns * 16 + lc] = f2bu(tacc[ns][r]);
        __syncthreads();

        f32x4 cacc[4] = {};
#pragma unroll
        for (int ns = 0; ns < 4; ns++) {
            const bf16* kp = kb + (size_t)(b * N2_ + j0 + ns * 16 + lc) * 512 + h * 64 + kq * 8;
            s16x8 kf0 = *reinterpret_cast<const s16x8*>(kp);
            s16x8 kf1 = *reinterpret_cast<const s16x8*>(kp + 32);
            cacc[ns] = MFMA16(qf0, kf0, cacc[ns]);
            cacc[ns] = MFMA16(qf1, kf1, cacc[ns]);
        }
        float Lv[4][4];
#pragma unroll
        for (int ns = 0; ns < 4; ns++) {
            int jloc = ns * 16 + lc;
#pragma unroll
            for (int r = 0; r < 4; r++) {
                int mm = (ibase + r) - jloc + 64;
                Lv[ns][r] = cacc[ns][r] + us2f(Ts[jloc][mm]);
            }
        }
#pragma unroll
        for (int r = 0; r < 4; r++) {
            float v = fmaxf(fmaxf(Lv[0][r], Lv[1][r]), fmaxf(Lv[2][r], Lv[3][r]));
            v = fmaxf(v, __shfl_xor(v, 1));
            v = fmaxf(v, __shfl_xor(v, 2));
            v = fmaxf(v, __shfl_xor(v, 4));
            v = fmaxf(v, __shfl_xor(v, 8));
            float mn = fmaxf(m_run[r], v);
            float alpha = __expf(m_run[r] - mn);
            m_run[r] = mn;
            float s = 0.f;
#pragma unroll
            for (int ns = 0; ns < 4; ns++) {
                float p = __expf(Lv[ns][r] - mn);
                Lv[ns][r] = p;
                s += p;
            }
            s += __shfl_xor(s, 1);
            s += __shfl_xor(s, 2);
            s += __shfl_xor(s, 4);
            s += __shfl_xor(s, 8);
            l_run[r] = l_run[r] * alpha + s;
#pragma unroll
            for (int ns6 = 0; ns6 < 6; ns6++) oacc[ns6][r] *= alpha;
        }
#pragma unroll
        for (int ns = 0; ns < 4; ns++)
#pragma unroll
            for (int r = 0; r < 4; r++)
                Ps[ibase + r][ns * 16 + lc] = f2bu(Lv[ns][r]);
#pragma unroll
        for (int kk = 0; kk < 2; kk++) {
            s16x8 pf = *reinterpret_cast<const s16x8*>(&Ps[wave * 16 + lc][kq * 8 + kk * 32]);
#pragma unroll
            for (int ns6 = 0; ns6 < 6; ns6++) {
                s16x8 vf = *reinterpret_cast<const s16x8*>(&Vs[ns6 * 16 + lc][kq * 8 + kk * 32]);
                oacc[ns6] = MFMA16(pf, vf, oacc[ns6]);
            }
        }
    }

    float invl[4];
#pragma unroll
    for (int r = 0; r < 4; r++) invl[r] = 1.f / l_run[r];
#pragma unroll
    for (int ns6 = 0; ns6 < 6; ns6++)
#pragma unroll
        for (int r = 0; r < 4; r++)
            out1[(size_t)(b * N1_ + i0 + ibase + r) * 768 + h * 96 + ns6 * 16 + lc]
                = f2b(oacc[ns6][r] * invl[r]);
    if (lc == 0) {
#pragma unroll
        for (int r = 0; r < 4; r++) {
            mst[(size_t)bh * N1_ + i0 + ibase + r] = m_run[r];
            lst[(size_t)bh * N1_ + i0 + ibase + r] = l_run[r];
        }
    }
}

// ---------------------------------------------------------------------------
// MFMA attention pass 2 (unchanged from R7-R9).
// ---------------------------------------------------------------------------
__global__ __launch_bounds__(256) void attn2_kernel(
    const bf16* __restrict__ qb, const bf16* __restrict__ kb,
    const bf16* __restrict__ kbb, const bf16* __restrict__ relq,
    const bf16* __restrict__ v1, bf16* __restrict__ out2halves,
    const float* __restrict__ mst, const float* __restrict__ lst)
{
    int half = blockIdx.x & 1;
    int jt = (blockIdx.x >> 1) & 7;
    int bh = blockIdx.x >> 4;
    int b = bh >> 3, h = bh & 7;
    int j0 = jt * 64;
    __shared__ __align__(16) unsigned short Ts[64][130];
    __shared__ __align__(16) unsigned short Ps[64][72];
    __shared__ __align__(16) unsigned short Vs[96][72];
    int tid = threadIdx.x, wave = tid >> 6, lane = tid & 63;
    int lc = lane & 15, kq = lane >> 4;
    int ibase = wave * 16 + kq * 4;

    const bf16* kbp = kbb + (size_t)(b * N2_ + j0 + wave * 16 + lc) * 512 + h * 64 + kq * 8;
    s16x8 kbf0 = *reinterpret_cast<const s16x8*>(kbp);
    s16x8 kbf1 = *reinterpret_cast<const s16x8*>(kbp + 32);
    s16x8 kf0[4], kf1[4];
#pragma unroll
    for (int ns = 0; ns < 4; ns++) {
        const bf16* kp = kb + (size_t)(b * N2_ + j0 + ns * 16 + lc) * 512 + h * 64 + kq * 8;
        kf0[ns] = *reinterpret_cast<const s16x8*>(kp);
        kf1[ns] = *reinterpret_cast<const s16x8*>(kp + 32);
    }

    f32x4 oacc[6] = {};
    for (int i0 = half * 1024; i0 < half * 1024 + 1024; i0 += 64) {
        __syncthreads();
        int m0 = i0 + 447 - j0;
        f32x4 tacc[8] = {};
#pragma unroll
        for (int ns = 0; ns < 8; ns++) {
            int row = m0 + ns * 16 + lc;
            if (row < 0) row = 0;
            const bf16* rp = relq + (size_t)row * 512 + h * 64 + kq * 8;
            s16x8 rf0 = *reinterpret_cast<const s16x8*>(rp);
            s16x8 rf1 = *reinterpret_cast<const s16x8*>(rp + 32);
            tacc[ns] = MFMA16(kbf0, rf0, tacc[ns]);
            tacc[ns] = MFMA16(kbf1, rf1, tacc[ns]);
        }
        {
            int ii = tid & 63, dvb = (tid >> 6) * 24;
            const unsigned short* vp = (const unsigned short*)
                (v1 + (size_t)(b * N1_ + i0 + ii) * 768 + h * 96 + dvb);
#pragma unroll
            for (int t = 0; t < 24; t++) Vs[dvb + t][ii] = vp[t];
        }
#pragma unroll
        for (int ns = 0; ns < 8; ns++)
#pragma unroll
            for (int r = 0; r < 4; r++)
                Ts[wave * 16 + kq * 4 + r][ns * 16 + lc] = f2bu(tacc[ns][r]);
        __syncthreads();

        const bf16* qp = qb + (size_t)(b * N1_ + i0 + wave * 16 + lc) * 512 + h * 64 + kq * 8;
        s16x8 qf0 = *reinterpret_cast<const s16x8*>(qp);
        s16x8 qf1 = *reinterpret_cast<const s16x8*>(qp + 32);
        f32x4 cacc[4] = {};
#pragma unroll
        for (int ns = 0; ns < 4; ns++) {
            cacc[ns] = MFMA16(qf0, kf0[ns], cacc[ns]);
            cacc[ns] = MFMA16(qf1, kf1[ns], cacc[ns]);
        }
        float mi[4], invli[4];
#pragma unroll
        for (int r = 0; r < 4; r++) {
            mi[r] = mst[(size_t)bh * N1_ + i0 + ibase + r];
            invli[r] = 1.f / lst[(size_t)bh * N1_ + i0 + ibase + r];
        }
#pragma unroll
        for (int ns = 0; ns < 4; ns++) {
            int jloc = ns * 16 + lc;
#pragma unroll
            for (int r = 0; r < 4; r++) {
                int mm = (ibase + r) - jloc + 64;
                float L = cacc[ns][r] + us2f(Ts[jloc][mm]);
                Ps[jloc][ibase + r] = f2bu(__expf(L - mi[r]) * invli[r]);
            }
        }
        __syncthreads();
#pragma unroll
        for (int kk = 0; kk < 2; kk++) {
            s16x8 pf = *reinterpret_cast<const s16x8*>(&Ps[wave * 16 + lc][kq * 8 + kk * 32]);
#pragma unroll
            for (int ns6 = 0; ns6 < 6; ns6++) {
                s16x8 vf = *reinterpret_cast<const s16x8*>(&Vs[ns6 * 16 + lc][kq * 8 + kk * 32]);
                oacc[ns6] = MFMA16(pf, vf, oacc[ns6]);
            }
        }
    }

    bf16* outp = out2halves + (size_t)half * B_ * N2_ * 768;
#pragma unroll
    for (int ns6 = 0; ns6 < 6; ns6++)
#pragma unroll
        for (int r = 0; r < 4; r++)
            outp[(size_t)(b * N2_ + j0 + ibase + r) * 768 + h * 96 + ns6 * 16 + lc]
                = f2b(oacc[ns6][r]);
}

// ---------------------------------------------------------------------------
extern "C" void kernel_launch(void* const* d_in, const int* in_sizes, int n_in,
                              void* d_out, int out_size, void* d_ws, size_t ws_size,
                              hipStream_t stream)
{
    (void)in_sizes; (void)n_in; (void)out_size; (void)ws_size;
    const float* x      = (const float*)d_in[0];
    const float* y0     = (const float*)d_in[1];
    const float* Wres   = (const float*)d_in[2];
    const float* lnx_g  = (const float*)d_in[3];
    const float* lnx_b  = (const float*)d_in[4];
    const float* lny_g  = (const float*)d_in[5];
    const float* lny_b  = (const float*)d_in[6];
    const float* Wq     = (const float*)d_in[7];
    const float* Wk     = (const float*)d_in[8];
    const float* Wv1    = (const float*)d_in[9];
    const float* Wv2    = (const float*)d_in[10];
    const float* Wo1    = (const float*)d_in[11];
    const float* bo1    = (const float*)d_in[12];
    const float* Wo2    = (const float*)d_in[13];
    const float* bo2    = (const float*)d_in[14];
    const float* Wrel   = (const float*)d_in[15];
    const float* rel_pb = (const float*)d_in[16];
    const float* fx_g   = (const float*)d_in[17];
    const float* fx_b   = (const float*)d_in[18];
    const float* fx_w1  = (const float*)d_in[19];
    const float* fx_b1  = (const float*)d_in[20];
    const float* fx_w2  = (const float*)d_in[21];
    const float* fx_b2  = (const float*)d_in[22];
    const float* fy_g   = (const float*)d_in[23];
    const float* fy_b   = (const float*)d_in[24];
    const float* fy_w1  = (const float*)d_in[25];
    const float* fy_b1  = (const float*)d_in[26];
    const float* fy_w2  = (const float*)d_in[27];
    const float* fy_b2  = (const float*)d_in[28];

    float* out_x = (float*)d_out;                          // [4,2048,768] fp32
    float* out_y = out_x + (size_t)B_ * N1_ * D_;          // [4,512,768] fp32
    bf16* out1 = (bf16*)d_out;  // attn out1 parked in d_out (dies before fp32 writes)

    // ---- workspace (~86 MB) ----
    char* W = (char*)d_ws;
    size_t o = 0;
    auto alloc = [&](size_t bytes) { char* p = W + o; o += (bytes + 255) & ~(size_t)255; return p; };
    bf16*   qb   = (bf16*)alloc((size_t)B_ * N1_ * 512 * 2);   // 8.39 MB ┐
    bf16*   kb   = (bf16*)alloc((size_t)B_ * N2_ * 512 * 2);   // 2.10 MB │ x4 overlays
    bf16*   posb = (bf16*)alloc((size_t)NPOS_ * 96 * 2);       // 0.79 MB │ this span
    bf16*   relq = (bf16*)alloc((size_t)NPOS_ * 512 * 2);      // 4.19 MB ┘
    bf16*   v1b  = (bf16*)alloc((size_t)B_ * N1_ * 768 * 2);   // 12.58 MB ┐ hx spans
    bf16*   hx2  = (bf16*)alloc((size_t)B_ * N1_ * 768 * 2);   // 12.58 MB ┘ both
    bf16*   v2b  = (bf16*)alloc((size_t)B_ * N2_ * 768 * 2);   // 3.15 MB  (y4 overlays)
    float*  yb   = (float*)alloc((size_t)B_ * N2_ * 768 * 4);  // 6.29 MB fp32 residual
    bf16*   kbbb = (bf16*)alloc((size_t)B_ * N2_ * 512 * 2);   // 2.10 MB
    bf16*   x1   = (bf16*)alloc((size_t)B_ * N1_ * 768 * 2);   // 12.58 MB ln(x); later ln(x4)
    bf16*   y1   = (bf16*)alloc((size_t)B_ * N2_ * 768 * 2);   // 3.15 MB ln(y); later ln(y4)
    bf16*   wpool= (bf16*)alloc((size_t)9093120 * 2);          // 17.34 MB W^T packed
    float*  mst  = (float*)alloc((size_t)B_ * H_ * N1_ * 4);
    float*  lst  = (float*)alloc((size_t)B_ * H_ * N1_ * 4);
    bf16* x4 = qb;            // after attention, qb..relq span is dead
    bf16* y4 = v2b;           // after attention, v2b is dead
    bf16* hx = v1b;           // FFNx hidden spans v1b+hx2 (after Wo2 done)
    bf16* out2h = hx2;        // two 3.15MB half-buffers inside hx2 (dead before hx)
    bf16* hy = v1b;           // FFNy hidden reuses (hx dead by then)
    bf16* x4ln = x1;          // ln(x4) reuses x1 (dead after QV1)
    bf16* y4ln = y1;

    // packed W^T offsets (elements)
    const unsigned OW_RES = 0, OW_QV1 = 1179648, OW_KV2 = 2162688, OW_O1 = 3145728,
                   OW_O2 = 3735552, OW_REL = 4325376, OW_FXW1 = 4374528,
                   OW_FXW2 = 5554176, OW_FYW1 = 6733824, OW_FYW2 = 7913472;

    PackT pa;
    const float* srcs[12] = {Wres, Wq, Wv1, Wk, Wv2, Wo1, Wo2, Wrel,
                             fx_w1, fx_w2, fy_w1, fy_w2};
    unsigned Ks[12] = {1536, 768, 768, 768, 768, 768, 768, 96, 768, 1536, 768, 1536};
    unsigned Nss[12] = {768, 512, 768, 512, 768, 768, 768, 512, 1536, 768, 1536, 768};
    unsigned dbs[12] = {OW_RES, OW_QV1, OW_QV1 + 393216, OW_KV2, OW_KV2 + 393216,
                        OW_O1, OW_O2, OW_REL, OW_FXW1, OW_FXW2, OW_FYW1, OW_FYW2};
    unsigned drs[12] = {1536, 768, 768, 768, 768, 768, 768, 96, 768, 1536, 768, 1536};
    unsigned cum = 0;
    for (int i = 0; i < 12; i++) {
        pa.src[i] = srcs[i]; pa.K[i] = Ks[i]; pa.N[i] = Nss[i];
        pa.dbase[i] = dbs[i]; pa.drow[i] = drs[i];
        pa.t0[i] = cum;
        cum += (Ks[i] >> 5) * (Nss[i] >> 6);
    }
    pa.t0[12] = cum;

    dim3 blk(256);
    // 0. transpose-pack weights
    packT_kernel<<<cum, blk, 0, stream>>>(pa, wpool);
    // 1. y = y0 @ W_res (fp32 A path, fp32 out)
    mgemm64_kernel<1, float, float><<<dim3(12, 32), blk, 0, stream>>>(
        y0, nullptr, wpool + OW_RES, yb, B_ * N2_, D_, 1536,
        nullptr, 0, nullptr, nullptr, nullptr, nullptr, nullptr, 0.f);
    // 2. LayerNorms materialized as bf16
    lnfull_kernel<float><<<B_ * N1_, 64, 0, stream>>>(x, lnx_g, lnx_b, x1);
    lnfull_kernel<float><<<B_ * N2_, 64, 0, stream>>>(yb, lny_g, lny_b, y1);
    // 3. fused projections [q|v1], [k|v2]+kbb (bf16 fast path)
    mgemm128_kernel<0, bf16, float><<<dim3(10, 64), blk, 0, stream>>>(
        x1, wpool + OW_QV1, (bf16*)nullptr, B_ * N1_, 1280, D_,
        nullptr, 0, nullptr, qb, v1b, SCALE_);
    mgemm64_kernel<0, bf16, float><<<dim3(20, 32), blk, 0, stream>>>(
        y1, nullptr, wpool + OW_KV2, (bf16*)nullptr, B_ * N2_, 1280, D_,
        nullptr, 0, nullptr, kb, v2b, kbbb, rel_pb, 1.f);
    // 4. positional features + rel_q
    pos_kernel<<<(NPOS_ + 63) / 64, 64, 0, stream>>>(posb);
    mgemm64_kernel<0, bf16, float><<<dim3(8, 64), blk, 0, stream>>>(
        posb, nullptr, wpool + OW_REL, relq, NPOS_, 512, 96,
        nullptr, 0, nullptr, nullptr, nullptr, nullptr, nullptr, 0.f);
    // 5. MFMA attention (unchanged)
    attn1_kernel<<<B_ * H_ * (N1_ / 64), blk, 0, stream>>>(
        qb, kb, kbbb, relq, v2b, out1, mst, lst);
    attn2_kernel<<<B_ * H_ * (N2_ / 64) * 2, blk, 0, stream>>>(
        qb, kb, kbbb, relq, v1b, out2h, mst, lst);
    // 6. output projections + residuals
    mgemm128_kernel<0, bf16, float><<<dim3(6, 64), blk, 0, stream>>>(
        out1, wpool + OW_O1, x4, B_ * N1_, D_, D_,
        bo1, 0, x, nullptr, nullptr, 0.f);
    mgemm64_kernel<2, bf16, float><<<dim3(12, 32), blk, 0, stream>>>(
        out2h, out2h + (size_t)B_ * N2_ * 768, wpool + OW_O2, y4, B_ * N2_, D_, D_,
        bo2, 0, yb, nullptr, nullptr, nullptr, nullptr, 0.f);
    // 7. FFN x -> out_x fp32
    lnfull_kernel<bf16><<<B_ * N1_, 64, 0, stream>>>(x4, fx_g, fx_b, x4ln);
    mgemm128_kernel<0, bf16, float><<<dim3(12, 64), blk, 0, stream>>>(
        x4ln, wpool + OW_FXW1, hx, B_ * N1_, 1536, D_,
        fx_b1, 1, nullptr, nullptr, nullptr, 0.f);
    mgemm128_kernel<0, float, bf16><<<dim3(6, 64), blk, 0, stream>>>(
        hx, wpool + OW_FXW2, out_x, B_ * N1_, D_, 1536,
        fx_b2, 0, x4, nullptr, nullptr, 0.f);
    // 8. FFN y -> out_y fp32 (hy reuses hx region; hx dead after FFNx-w2)
    lnfull_kernel<bf16><<<B_ * N2_, 64, 0, stream>>>(y4, fy_g, fy_b, y4ln);
    mgemm64_kernel<0, bf16, float><<<dim3(24, 32), blk, 0, stream>>>(
        y4ln, nullptr, wpool + OW_FYW1, hy, B_ * N2_, 1536, D_,
        fy_b1, 1, nullptr, nullptr, nullptr, nullptr, nullptr, 0.f);
    mgemm64_kernel<0, float, bf16><<<dim3(12, 32), blk, 0, stream>>>(
        hy, nullptr, wpool + OW_FYW2, out_y, B_ * N2_, D_, 1536,
        fy_b2, 0, y4, nullptr, nullptr, nullptr, nullptr, 0.f);
}